// Round 17
// baseline (1103.425 us; speedup 1.0000x reference)
//
#include <hip/hip_runtime.h>

typedef __bf16 bf16;
typedef __bf16 bf16x4 __attribute__((ext_vector_type(4)));
typedef __bf16 bf16x8 __attribute__((ext_vector_type(8)));
typedef float  f32x4  __attribute__((ext_vector_type(4)));

static constexpr int kC   = 1024;
static constexpr int kT   = 1024;
static constexpr int kB   = 4;
static constexpr int kH   = 16;
static constexpr int kHD  = 64;
static constexpr int kL   = 4;
static constexpr int kFF  = 100;
static constexpr int kFFP = 128;
static constexpr int kM   = kB * kT;

__device__ __forceinline__ void gload16(const bf16* g, bf16* l)
{
    __builtin_amdgcn_global_load_lds(
        (const __attribute__((address_space(1))) void*)g,
        (__attribute__((address_space(3))) void*)l, 16, 0, 0);
}

__device__ __forceinline__ unsigned bpack(float a, float b)
{
    bf16 x = (bf16)a, y = (bf16)b;
    unsigned short ux = __builtin_bit_cast(unsigned short, x);
    unsigned short uy = __builtin_bit_cast(unsigned short, y);
    return (unsigned)ux | ((unsigned)uy << 16);
}
__device__ __forceinline__ float blo(unsigned u) { return __builtin_bit_cast(float, u << 16); }
__device__ __forceinline__ float bhi(unsigned u) { return __builtin_bit_cast(float, u & 0xffff0000u); }

// ---------------------------------------------------------------------------
// One-shot prep: all weight transposes/converts + bias pack + pooled zero.
// ---------------------------------------------------------------------------
__global__ __launch_bounds__(256)
void prep_kernel(const float* __restrict__ Wq, const float* __restrict__ Wk,
                 const float* __restrict__ Wv, const float* __restrict__ Wo,
                 const float* __restrict__ W1, const float* __restrict__ W2,
                 const float* __restrict__ bq, const float* __restrict__ bk,
                 const float* __restrict__ bv,
                 bf16* __restrict__ WQKVT, bf16* __restrict__ WOT,
                 bf16* __restrict__ W1T, bf16* __restrict__ W2T,
                 float* __restrict__ BQKV, float* __restrict__ pooled)
{
    __shared__ float tile[32][33];
    const int bid = blockIdx.x, tid = threadIdx.x;
    const float* src; bf16* dst; int K, N, KP, NP, bx, by;
    if (bid < 12288) {
        const int slab = bid >> 10, within = bid & 1023;
        const int l = slab / 3, which = slab % 3;
        const float* W = (which == 0) ? Wq : (which == 1) ? Wk : Wv;
        src = W + (long)l * kC * kC;
        dst = WQKVT + (long)l * 3 * kC * kC + (long)which * kC * kC;
        K = N = KP = NP = kC; bx = within & 31; by = within >> 5;
    } else if (bid < 16384) {
        const int t = bid - 12288, z = t >> 10, within = t & 1023;
        src = Wo + (long)z * kC * kC; dst = WOT + (long)z * kC * kC;
        K = N = KP = NP = kC; bx = within & 31; by = within >> 5;
    } else if (bid < 16896) {
        const int t = bid - 16384, z = t >> 7, within = t & 127;
        src = W1 + (long)z * kC * kFF; dst = W1T + (long)z * kFFP * kC;
        K = kC; N = kFF; KP = kC; NP = kFFP; bx = within & 3; by = within >> 2;
    } else if (bid < 17408) {
        const int t = bid - 16896, z = t >> 7, within = t & 127;
        src = W2 + (long)z * kFF * kC; dst = W2T + (long)z * kC * kFFP;
        K = kFF; N = kC; KP = kFFP; NP = kC; bx = within & 31; by = within >> 5;
    } else if (bid < 17456) {
        const int gid = (bid - 17408) * 256 + tid;
        const int l = gid / (3 * kC), wq = (gid / kC) % 3, c = gid & (kC - 1);
        const float* s = (wq == 0) ? bq : (wq == 1) ? bk : bv;
        BQKV[gid] = s[l * kC + c];
        return;
    } else {
        const int i = (bid - 17456) * 256 + tid;
        if (i < kB * kC) pooled[i] = 0.f;
        return;
    }
    const int n0 = bx * 32, k0 = by * 32;
    const int tx = tid & 31, ty = tid >> 5;
#pragma unroll
    for (int i = 0; i < 4; ++i) {
        int k = k0 + ty + i * 8, n = n0 + tx;
        tile[ty + i * 8][tx] = (k < K && n < N) ? src[(long)k * N + n] : 0.f;
    }
    __syncthreads();
#pragma unroll
    for (int i = 0; i < 4; ++i) {
        int n = n0 + ty + i * 8, k = k0 + tx;
        if (n < NP && k < KP) dst[(long)n * KP + k] = (bf16)tile[tx][ty + i * 8];
    }
}

__global__ __launch_bounds__(256)
void embed_kernel(const int* __restrict__ idx, const float* __restrict__ tok,
                  const float* __restrict__ pos, float* __restrict__ x)
{
    const int m = blockIdx.x;
    const int c = threadIdx.x * 4;
    const int t = m & (kT - 1);
    const long tk = (long)idx[m] * kC;
    float4 a = *(const float4*)&tok[tk + c];
    float4 b = *(const float4*)&pos[(long)t * kC + c];
    float4 o; o.x = a.x + b.x; o.y = a.y + b.y; o.z = a.z + b.z; o.w = a.w + b.w;
    *(float4*)&x[(long)m * kC + c] = o;
}

__global__ __launch_bounds__(256)
void ln_kernel(const float* __restrict__ x, const float* __restrict__ g,
               const float* __restrict__ be, bf16* __restrict__ ob)
{
    __shared__ float red[8];
    const long row = blockIdx.x;
    const int tid = threadIdx.x, lane = tid & 63, wv = tid >> 6;
    const float4 v = *(const float4*)&x[row * kC + tid * 4];
    float s = v.x + v.y + v.z + v.w;
    float s2 = v.x * v.x + v.y * v.y + v.z * v.z + v.w * v.w;
#pragma unroll
    for (int o = 32; o > 0; o >>= 1) { s += __shfl_down(s, o); s2 += __shfl_down(s2, o); }
    if (!lane) { red[wv] = s; red[4 + wv] = s2; }
    __syncthreads();
    s  = red[0] + red[1] + red[2] + red[3];
    s2 = red[4] + red[5] + red[6] + red[7];
    const float mean = s * (1.f / kC);
    const float var  = s2 * (1.f / kC) - mean * mean;
    const float rstd = rsqrtf(var + 1e-5f);
    const float4 gg = *(const float4*)&g[tid * 4];
    const float4 bb = *(const float4*)&be[tid * 4];
    bf16x4 o;
    o[0] = (bf16)((v.x - mean) * rstd * gg.x + bb.x);
    o[1] = (bf16)((v.y - mean) * rstd * gg.y + bb.y);
    o[2] = (bf16)((v.z - mean) * rstd * gg.z + bb.z);
    o[3] = (bf16)((v.w - mean) * rstd * gg.w + bb.w);
    *(bf16x4*)&ob[row * kC + tid * 4] = o;
}

// ---------------------------------------------------------------------------
// MFMA GEMM: C = A * B^T.  GL=1: global_load_lds staging (BM/BN mult of 32).
// MODE 0: QKV (z=0 q*0.125*log2e -> [B,H,T,HD]; z=1 k; z=2 v -> VT)
// MODE 4: resid += acc + bias
// ---------------------------------------------------------------------------
template<int WAVES_M, int WAVES_N, int AI, int BJ, int MODE, int GL>
__global__ __launch_bounds__(256)
void gemm_bf16(const bf16* __restrict__ Ag, long strideA,
               const bf16* __restrict__ Bg, long strideB,
               const float* __restrict__ bias, int strideBias,
               bf16* __restrict__ outb, long strideOut,
               float* __restrict__ resid,
               int N, int K, int lda, int ldb)
{
    constexpr int BM = WAVES_M * AI * 16;
    constexpr int BN = WAVES_N * BJ * 16;
    constexpr int BK = 64;
    constexpr int LK = GL ? BK : (BK + 8);
    __shared__ __align__(16) bf16 As[BM * LK];
    __shared__ __align__(16) bf16 Bs[BN * LK];
    const int tid = threadIdx.x, lane = tid & 63, wv = tid >> 6;
    const int wm = wv / WAVES_N, wn = wv % WAVES_N;
    const int lr = lane & 15, lg = lane >> 4;
    const int z = blockIdx.z;
    const bf16* A = Ag + (long)z * strideA;
    const bf16* B = Bg + (long)z * strideB;
    const float* bi = bias ? bias + (long)z * strideBias : nullptr;
    const int m0 = blockIdx.y * BM, n0 = blockIdx.x * BN;

    f32x4 acc[AI][BJ];
#pragma unroll
    for (int i = 0; i < AI; ++i)
#pragma unroll
        for (int j = 0; j < BJ; ++j) acc[i][j] = (f32x4){0.f, 0.f, 0.f, 0.f};

    for (int k0 = 0; k0 < K; k0 += BK) {
        if constexpr (GL) {
            static_assert((BM % 32) == 0 && (BN % 32) == 0, "GL tile multiple of 32");
            const int sr  = lane >> 3;
            const int gcb = (lane & 7) ^ sr;
            constexpr int ARW = BM / 4;
            constexpr int BRW = BN / 4;
#pragma unroll
            for (int p = 0; p < BM / 32; ++p)
                gload16(A + (long)(m0 + wv * ARW + p * 8 + sr) * lda + k0 + gcb * 8,
                        &As[(wv * ARW + p * 8) * BK]);
#pragma unroll
            for (int p = 0; p < BN / 32; ++p)
                gload16(B + (long)(n0 + wv * BRW + p * 8 + sr) * ldb + k0 + gcb * 8,
                        &Bs[(wv * BRW + p * 8) * BK]);
        } else {
            constexpr int AP = (BM * BK) / (256 * 8);
#pragma unroll
            for (int p = 0; p < AP; ++p) {
                int r = p * 32 + (tid >> 3), c = (tid & 7) * 8;
                *(uint4*)&As[r * LK + c] = *(const uint4*)&A[(long)(m0 + r) * lda + k0 + c];
            }
            constexpr int BP = (BN * BK) / (256 * 8);
#pragma unroll
            for (int p = 0; p < BP; ++p) {
                int r = p * 32 + (tid >> 3), c = (tid & 7) * 8;
                *(uint4*)&Bs[r * LK + c] = *(const uint4*)&B[(long)(n0 + r) * ldb + k0 + c];
            }
        }
        __syncthreads();
#pragma unroll
        for (int kk = 0; kk < 2; ++kk) {
            bf16x8 af[AI], bfv[BJ];
#pragma unroll
            for (int i = 0; i < AI; ++i) {
                const int r = wm * AI * 16 + i * 16 + lr;
                const int c = GL ? (((kk * 4 + lg) ^ (lr & 7)) * 8) : (kk * 32 + lg * 8);
                af[i] = *(const bf16x8*)&As[r * LK + c];
            }
#pragma unroll
            for (int j = 0; j < BJ; ++j) {
                const int r = wn * BJ * 16 + j * 16 + lr;
                const int c = GL ? (((kk * 4 + lg) ^ (lr & 7)) * 8) : (kk * 32 + lg * 8);
                bfv[j] = *(const bf16x8*)&Bs[r * LK + c];
            }
#pragma unroll
            for (int i = 0; i < AI; ++i)
#pragma unroll
                for (int j = 0; j < BJ; ++j)
                    acc[i][j] = __builtin_amdgcn_mfma_f32_16x16x32_bf16(af[i], bfv[j], acc[i][j], 0, 0, 0);
        }
        __syncthreads();
    }

#pragma unroll
    for (int i = 0; i < AI; ++i)
#pragma unroll
        for (int j = 0; j < BJ; ++j)
#pragma unroll
            for (int rr = 0; rr < 4; ++rr) {
                const int grow = m0 + wm * AI * 16 + i * 16 + lg * 4 + rr;
                const int gcol = n0 + wn * BJ * 16 + j * 16 + lr;
                float v = acc[i][j][rr];
                if constexpr (MODE == 0) {
                    v += bi[gcol];
                    if (z == 0) v *= 0.125f * 1.44269504f;  // scale * log2(e)
                    const int b = grow >> 10, t = grow & (kT - 1);
                    const int hh = gcol >> 6, hd = gcol & 63;
                    long o = (long)z * strideOut;
                    if (z == 2) o += (((long)b * kH + hh) * kHD + hd) * kT + t;  // VT
                    else        o += (((long)b * kH + hh) * kT + t) * kHD + hd;  // Q/K
                    outb[o] = (bf16)v;
                } else {
                    v += bi[gcol];
                    resid[(long)grow * N + gcol] += v;
                }
            }
}

// ---------------------------------------------------------------------------
// Fused FF: ln2 + FF1(relu) + FF2(+=X), one block per 16 rows, 4 waves.
// ---------------------------------------------------------------------------
__global__ __launch_bounds__(256, 2)
void ff_fused(float* __restrict__ X, const float* __restrict__ g,
              const float* __restrict__ be,
              const bf16* __restrict__ W1T_, const float* __restrict__ b1_,
              const bf16* __restrict__ W2T_, const float* __restrict__ b2_)
{
    __shared__ __align__(16) bf16 Hs[16 * kC];
    __shared__ __align__(16) bf16 F1s[16 * kFFP];
    const int tid = threadIdx.x, lane = tid & 63, w = tid >> 6;
    const int lr = lane & 15, lg = lane >> 4;
    const int r0 = blockIdx.x * 16;

    {
        const int row = tid >> 4, c16 = tid & 15;
        float4 xv[16];
        float s1 = 0.f, s2 = 0.f;
#pragma unroll
        for (int p = 0; p < 8; ++p) {
            const float* base = &X[(long)(r0 + row) * kC + p * 128 + c16 * 8];
            xv[2 * p]     = *(const float4*)base;
            xv[2 * p + 1] = *(const float4*)(base + 4);
#pragma unroll
            for (int e = 0; e < 4; ++e) {
                float a0 = ((const float*)&xv[2 * p])[e], a1 = ((const float*)&xv[2 * p + 1])[e];
                s1 += a0 + a1; s2 += a0 * a0 + a1 * a1;
            }
        }
#pragma unroll
        for (int off = 1; off < 16; off <<= 1) { s1 += __shfl_xor(s1, off); s2 += __shfl_xor(s2, off); }
        const float mean = s1 * (1.f / kC);
        const float rstd = rsqrtf(s2 * (1.f / kC) - mean * mean + 1e-5f);
#pragma unroll
        for (int p = 0; p < 8; ++p) {
            const int c0 = p * 128 + c16 * 8;
            float4 g0 = *(const float4*)&g[c0],  g1 = *(const float4*)&g[c0 + 4];
            float4 b0 = *(const float4*)&be[c0], b1v = *(const float4*)&be[c0 + 4];
            float h[8];
#pragma unroll
            for (int e = 0; e < 4; ++e) {
                h[e]     = (((const float*)&xv[2 * p])[e]     - mean) * rstd * ((const float*)&g0)[e] + ((const float*)&b0)[e];
                h[4 + e] = (((const float*)&xv[2 * p + 1])[e] - mean) * rstd * ((const float*)&g1)[e] + ((const float*)&b1v)[e];
            }
            uint4 hv;
            hv.x = bpack(h[0], h[1]); hv.y = bpack(h[2], h[3]);
            hv.z = bpack(h[4], h[5]); hv.w = bpack(h[6], h[7]);
            const int cb = c16 + p * 16;
            *(uint4*)&Hs[row * kC + ((cb ^ (row & 7)) << 3)] = hv;
        }
    }
    __syncthreads();

    {
        f32x4 accA[2], accB[2];
#pragma unroll
        for (int j = 0; j < 2; ++j) { accA[j] = (f32x4){0,0,0,0}; accB[j] = (f32x4){0,0,0,0}; }
        for (int k0 = 0; k0 < kC; k0 += 64) {
            const bf16x8 a0 = *(const bf16x8*)&Hs[lr * kC + ((((k0 >> 3) + 0 * 4 + lg) ^ (lr & 7)) << 3)];
            const bf16x8 a1 = *(const bf16x8*)&Hs[lr * kC + ((((k0 >> 3) + 1 * 4 + lg) ^ (lr & 7)) << 3)];
#pragma unroll
            for (int j = 0; j < 2; ++j) {
                const bf16x8 b0 = *(const bf16x8*)&W1T_[(long)(w * 32 + j * 16 + lr) * kC + k0 + 0 * 32 + lg * 8];
                const bf16x8 b1 = *(const bf16x8*)&W1T_[(long)(w * 32 + j * 16 + lr) * kC + k0 + 1 * 32 + lg * 8];
                accA[j] = __builtin_amdgcn_mfma_f32_16x16x32_bf16(a0, b0, accA[j], 0, 0, 0);
                accB[j] = __builtin_amdgcn_mfma_f32_16x16x32_bf16(a1, b1, accB[j], 0, 0, 0);
            }
        }
#pragma unroll
        for (int j = 0; j < 2; ++j)
#pragma unroll
            for (int rr = 0; rr < 4; ++rr) {
                const int row = lg * 4 + rr, col = w * 32 + j * 16 + lr;
                float v = accA[j][rr] + accB[j][rr] + (col < kFF ? b1_[col] : 0.f);
                F1s[row * kFFP + (((col >> 3) ^ (row & 7)) << 3) + (col & 7)] = (bf16)fmaxf(v, 0.f);
            }
    }
    __syncthreads();

    for (int nc = 0; nc < 8; ++nc) {
        f32x4 acc[2];
        acc[0] = (f32x4){0.f, 0.f, 0.f, 0.f};
        acc[1] = (f32x4){0.f, 0.f, 0.f, 0.f};
#pragma unroll
        for (int kk = 0; kk < 4; ++kk) {
            const bf16x8 a = *(const bf16x8*)&F1s[lr * kFFP + (((kk * 4 + lg) ^ (lr & 7)) << 3)];
#pragma unroll
            for (int j = 0; j < 2; ++j) {
                const bf16x8 bv = *(const bf16x8*)&W2T_[(long)(nc * 128 + w * 32 + j * 16 + lr) * kFFP + kk * 32 + lg * 8];
                acc[j] = __builtin_amdgcn_mfma_f32_16x16x32_bf16(a, bv, acc[j], 0, 0, 0);
            }
        }
#pragma unroll
        for (int j = 0; j < 2; ++j)
#pragma unroll
            for (int rr = 0; rr < 4; ++rr) {
                const int row = r0 + lg * 4 + rr, col = nc * 128 + w * 32 + j * 16 + lr;
                X[(long)row * kC + col] += acc[j][rr] + b2_[col];
            }
    }
}

// ---------------------------------------------------------------------------
// Fused attention v15: KVBLK=128, SINGLE-buffered wave-private K/V + depth-1
// register prefetch. K/V LDS rows are wave-private (wave w stages AND reads
// only its own rows), so tile overwrite needs no cross-wave barrier — only
// the same-wave ds_write->ds_read order the compiler already enforces.
// Per b: 8 phases x {reg-load kt+1 | QK^T(4 MFMA) | exp2 -> Ps | lgkm-barrier
// | PV(4 MFMA) | ds_write kt+1}, then 1 reduction barrier. 9 barriers/b.
// LDS: K[128][64] 16K + V[64][128] 16K + Ps[16][1024] 32K = 64 KB -> 2/CU.
// ---------------------------------------------------------------------------
__global__ __launch_bounds__(256, 2)
void attn_fused(const bf16* __restrict__ Qg, const bf16* __restrict__ Kg,
                const bf16* __restrict__ VTg, bf16* __restrict__ yg,
                float* __restrict__ attm)
{
    __shared__ __align__(16) bf16 SH[32768];   // 64 KB total
    bf16* Klds = SH;                           // [128][64]
    bf16* Vlds = SH + 8192;                    // [64][128]
    bf16* Ps   = SH + 16384;                   // [16][1024] swizzled E
    __shared__ __align__(16) float reds[16][4];
    __shared__ float invs[16];
    const int tid = threadIdx.x, lane = tid & 63, w = tid >> 6;   // w 0..3
    const int lr = lane & 15, lg = lane >> 4;
    const int bid = blockIdx.x, r_ = bid >> 3;
    const int h = ((bid & 7) << 1) | (r_ & 1);    // XCD-local head
    const int q0 = (r_ >> 1) * 16;

    const int sr  = lane >> 3;                 // K staging: row within 8-row chunk
    const int gcb = (lane & 7) ^ sr;           // K inverse-swizzled src col-block
    const int loB = (lg & 1) * 4;
    const int wr8 = lane * 8;                  // K LDS linear 16B slot

    unsigned am_[16][2];                       // attm acc (q=lr), packed bf16x2
#pragma unroll
    for (int j = 0; j < 16; ++j) { am_[j][0] = 0u; am_[j][1] = 0u; }

    for (int b = 0; b < kB; ++b) {
        const long bh = (long)b * kH + h;
        const bf16* Qb = Qg + (bh * kT + q0) * kHD;
        const bf16* Kb = Kg + bh * kT * kHD;
        const bf16* Vb = VTg + bh * (long)kHD * kT;

        // Q fragments (tiny, L2-hot)
        const bf16x8 qf0 = *(const bf16x8*)&Qb[lr * kHD + lg * 8];
        const bf16x8 qf1 = *(const bf16x8*)&Qb[lr * kHD + 32 + lg * 8];

        uint4 kR[4], vR[4];
        // warmup: reg-load tile 0 and write it (single vmcnt drain per b)
#pragma unroll
        for (int c = 0; c < 4; ++c) {
            kR[c] = *(const uint4*)(Kb + (w * 32 + c * 8 + sr) * kHD + gcb * 8);
            const int vr = w * 16 + c * 4 + (lane >> 4);
            const int vs = (lane & 15) ^ ((c * 4 + (lane >> 4)) & 7);
            vR[c] = *(const uint4*)(Vb + (long)vr * kT + vs * 8);
        }
#pragma unroll
        for (int c = 0; c < 4; ++c) {
            *(uint4*)&Klds[(w * 32 + c * 8) * 64 + wr8] = kR[c];
            const int vr = w * 16 + c * 4 + (lane >> 4);
            *(uint4*)&Vlds[vr * 128 + (lane & 15) * 8] = vR[c];
        }

        float s = 0.f;
        f32x4 y0 = (f32x4){0.f, 0.f, 0.f, 0.f};
        f32x4 y1 = (f32x4){0.f, 0.f, 0.f, 0.f};

#pragma unroll
        for (int kt = 0; kt < 8; ++kt) {
            // 1) issue reg loads for tile kt+1 (consumed at end of this phase)
            if (kt < 7) {
                const int kn = (kt + 1) * 128;
#pragma unroll
                for (int c = 0; c < 4; ++c) {
                    kR[c] = *(const uint4*)(Kb + (kn + w * 32 + c * 8 + sr) * kHD + gcb * 8);
                    const int vr = w * 16 + c * 4 + (lane >> 4);
                    const int vs = (lane & 15) ^ ((c * 4 + (lane >> 4)) & 7);
                    vR[c] = *(const uint4*)(Vb + (long)vr * kT + kn + vs * 8);
                }
            }

            // 2) QK^T: wave w owns t-rows w*32..+31 of this 128-tile
            f32x4 acc[2];
            acc[0] = (f32x4){0.f, 0.f, 0.f, 0.f};
            acc[1] = (f32x4){0.f, 0.f, 0.f, 0.f};
#pragma unroll
            for (int j2 = 0; j2 < 2; ++j2) {
                const int krow = w * 32 + j2 * 16 + lr;
                const bf16x8 kf0 = *(const bf16x8*)&Klds[krow * 64 + (((0 + lg) ^ (lr & 7)) << 3)];
                const bf16x8 kf1 = *(const bf16x8*)&Klds[krow * 64 + (((4 + lg) ^ (lr & 7)) << 3)];
                acc[j2] = __builtin_amdgcn_mfma_f32_16x16x32_bf16(kf0, qf0, acc[j2], 0, 0, 0);
                acc[j2] = __builtin_amdgcn_mfma_f32_16x16x32_bf16(kf1, qf1, acc[j2], 0, 0, 0);
            }
            // exp2 + row-sum + E -> Ps (disjoint cols per (kt,w,j2))
#pragma unroll
            for (int j2 = 0; j2 < 2; ++j2) {
                const float e0 = exp2f(acc[j2][0]), e1 = exp2f(acc[j2][1]);
                const float e2 = exp2f(acc[j2][2]), e3 = exp2f(acc[j2][3]);
                s += (e0 + e1) + (e2 + e3);
                const int tb = kt * 16 + w * 4 + j2 * 2 + (lg >> 1);
                uint2 pk; pk.x = bpack(e0, e1); pk.y = bpack(e2, e3);
                *(uint2*)&Ps[lr * kT + ((tb ^ (lr & 7)) << 3) + loB] = pk;
            }

            // 3) single cross-wave barrier: E visible (lgkm only)
            asm volatile("s_waitcnt lgkmcnt(0)" ::: "memory");
            __builtin_amdgcn_s_barrier();
            __builtin_amdgcn_sched_barrier(0);

            // 4) PV: wave w owns d-slice w*16; 4 k-chunks, dual chains
            const int vrow = w * 16 + lr;
#pragma unroll
            for (int kc = 0; kc < 4; ++kc) {
                const bf16x8 a = *(const bf16x8*)&Ps[lr * kT + (((kt * 16 + kc * 4 + lg) ^ (lr & 7)) << 3)];
                const bf16x8 v = *(const bf16x8*)&Vlds[vrow * 128 + (((kc * 4 + lg) ^ (lr & 7)) << 3)];
                if (kc & 1) y1 = __builtin_amdgcn_mfma_f32_16x16x32_bf16(a, v, y1, 0, 0, 0);
                else        y0 = __builtin_amdgcn_mfma_f32_16x16x32_bf16(a, v, y0, 0, 0, 0);
            }

            // 5) overwrite own K/V rows with tile kt+1 (wave-private; compiler
            //    inserts counted vmcnt for the reg deps, lgkm orders vs next read)
            if (kt < 7) {
#pragma unroll
                for (int c = 0; c < 4; ++c) {
                    *(uint4*)&Klds[(w * 32 + c * 8) * 64 + wr8] = kR[c];
                    const int vr = w * 16 + c * 4 + (lane >> 4);
                    *(uint4*)&Vlds[vr * 128 + (lane & 15) * 8] = vR[c];
                }
            }
        }

        // row sums -> inv
        s += __shfl_xor(s, 16);
        s += __shfl_xor(s, 32);
        if (lane < 16) reds[lane][w] = s;
        asm volatile("s_waitcnt lgkmcnt(0)" ::: "memory");
        __builtin_amdgcn_s_barrier();
        __builtin_amdgcn_sched_barrier(0);
        float4 rv = *(const float4*)&reds[lr][0];
        const float inv = __builtin_amdgcn_rcpf((rv.x + rv.y) + (rv.z + rv.w));
        const float iv4 = inv * 0.25f;
        if (lane < 16) invs[lane] = inv;

        // am += E * inv/4  (each thread reads back ONLY its own E dwords,
        // so the next b's Ps writes — also own-thread — cannot race this)
#pragma unroll
        for (int kt = 0; kt < 8; ++kt)
#pragma unroll
            for (int j2 = 0; j2 < 2; ++j2) {
                const int tb = kt * 16 + w * 4 + j2 * 2 + (lg >> 1);
                uint2 e2v = *(const uint2*)&Ps[lr * kT + ((tb ^ (lr & 7)) << 3) + loB];
#pragma unroll
                for (int d = 0; d < 2; ++d) {
                    unsigned ev = d ? e2v.y : e2v.x;
                    unsigned av = am_[kt * 2 + j2][d];
                    float n0 = blo(av) + blo(ev) * iv4;
                    float n1 = bhi(av) + bhi(ev) * iv4;
                    am_[kt * 2 + j2][d] = bpack(n0, n1);
                }
            }

        // y write (row q = lg*4+rr, col d = w*16+lr)
#pragma unroll
        for (int rr = 0; rr < 4; ++rr) {
            const float iv = invs[lg * 4 + rr];
            yg[((long)b * kT + q0 + lg * 4 + rr) * kC + h * kHD + w * 16 + lr]
                = (bf16)((y0[rr] + y1[rr]) * iv);
        }
    }

    __syncthreads();   // all Ps/K/V reads done before fp32 reuse of SH
    // attm epilogue: stage [16][1024] fp32 in SH, stream out coalesced
    float* amf = (float*)SH;
#pragma unroll
    for (int kt = 0; kt < 8; ++kt)
#pragma unroll
        for (int j2 = 0; j2 < 2; ++j2)
#pragma unroll
            for (int d = 0; d < 2; ++d) {
                unsigned av = am_[kt * 2 + j2][d];
                const int col = kt * 128 + w * 32 + j2 * 16 + lg * 4 + 2 * d;
                amf[lr * kT + col]     = blo(av);
                amf[lr * kT + col + 1] = bhi(av);
            }
    __syncthreads();
#pragma unroll
    for (int p = 0; p < 16; ++p) {
        const int f = p * 256 + tid;              // 4096 float4s
        const int row = f >> 8, c4 = f & 255;
        float4 v = *(const float4*)&amf[row * kT + c4 * 4];
        *(float4*)&attm[((long)h * kT + q0 + row) * kT + c4 * 4] = v;
    }
}

// pooled[b][c] = mean_t hb[b,t,c]  (bf16 input)
__global__ __launch_bounds__(256)
void pool_kernel(const bf16* __restrict__ hb, float* __restrict__ pooled)
{
    const int c = blockIdx.x * 256 + threadIdx.x;
    const int b = blockIdx.y;
    const int t0 = blockIdx.z * 128;
    float s = 0.f;
    for (int t = t0; t < t0 + 128; ++t) s += (float)hb[((long)b * kT + t) * kC + c];
    atomicAdd(&pooled[b * kC + c], s * (1.f / kT));
}

// ---------------------------------------------------------------------------
extern "C" void kernel_launch(void* const* d_in, const int* in_sizes, int n_in,
                              void* d_out, int out_size, void* d_ws, size_t ws_size,
                              hipStream_t stream)
{
    const int*   idx  = (const int*)d_in[0];
    const float* tok  = (const float*)d_in[1];
    const float* pos  = (const float*)d_in[2];
    const float* Wq   = (const float*)d_in[3];
    const float* bq   = (const float*)d_in[4];
    const float* Wk   = (const float*)d_in[5];
    const float* bk   = (const float*)d_in[6];
    const float* Wv   = (const float*)d_in[7];
    const float* bv   = (const float*)d_in[8];
    const float* Wo   = (const float*)d_in[9];
    const float* bo   = (const float*)d_in[10];
    const float* ln1w = (const float*)d_in[11];
    const float* ln1b = (const float*)d_in[12];
    const float* ln2w = (const float*)d_in[13];
    const float* ln2b = (const float*)d_in[14];
    const float* W1   = (const float*)d_in[15];
    const float* b1   = (const float*)d_in[16];
    const float* W2   = (const float*)d_in[17];
    const float* b2   = (const float*)d_in[18];
    const float* lnfw = (const float*)d_in[19];
    const float* lnfb = (const float*)d_in[20];

    char* ws = (char*)d_ws;
    long off = 0;
    auto alloc = [&](long bytes) { char* p = ws + off; off += (bytes + 255) & ~255L; return p; };
    bf16*  WQKVT = (bf16*)alloc((long)kL * 3 * kC * kC * 2);
    bf16*  WOT   = (bf16*)alloc((long)kL * kC * kC * 2);
    bf16*  W1T   = (bf16*)alloc((long)kL * kFFP * kC * 2);
    bf16*  W2T   = (bf16*)alloc((long)kL * kC * kFFP * 2);
    float* BQKV  = (float*)alloc((long)kL * 3 * kC * 4);
    float* X     = (float*)alloc((long)kM * kC * 4);
    bf16*  Hbuf  = (bf16*)alloc((long)kM * kC * 2);
    bf16*  QKV   = (bf16*)alloc(3L * kM * kC * 2);
    bf16*  Y     = (bf16*)alloc((long)kM * kC * 2);

    float* pooled = (float*)d_out;
    float* attm_base = pooled + kB * kC;

    prep_kernel<<<17472, 256, 0, stream>>>(Wq, Wk, Wv, Wo, W1, W2, bq, bk, bv,
                                           WQKVT, WOT, W1T, W2T, BQKV, pooled);
    embed_kernel<<<kM, 256, 0, stream>>>(idx, tok, pos, X);

    for (int l = 0; l < kL; ++l) {
        ln_kernel<<<kM, 256, 0, stream>>>(X, ln1w + l * kC, ln1b + l * kC, Hbuf);
        gemm_bf16<2, 2, 4, 4, 0, 1><<<dim3(8, 32, 3), 256, 0, stream>>>(
            Hbuf, 0L, WQKVT + (long)l * 3 * kC * kC, (long)kC * kC,
            BQKV + l * 3 * kC, kC, QKV, (long)kM * kC, nullptr,
            kC, kC, kC, kC);
        attn_fused<<<dim3(1024), 256, 0, stream>>>(
            QKV, QKV + (long)kM * kC, QKV + 2L * kM * kC, Y,
            attm_base + (long)l * kH * kT * kT);
        gemm_bf16<2, 2, 4, 4, 4, 1><<<dim3(8, 32, 1), 256, 0, stream>>>(
            Y, 0L, WOT + (long)l * kC * kC, 0L, bo + l * kC, 0,
            nullptr, 0L, X, kC, kC, kC, kC);
        ff_fused<<<256, 256, 0, stream>>>(X, ln2w + l * kC, ln2b + l * kC,
                                          W1T + (long)l * kFFP * kC, b1 + l * kFF,
                                          W2T + (long)l * kC * kFFP, b2 + l * kC);
    }
    ln_kernel<<<kM, 256, 0, stream>>>(X, lnfw, lnfb, Hbuf);
    pool_kernel<<<dim3(4, kB, 8), 256, 0, stream>>>(Hbuf, pooled);
}

// Round 18
// 817.354 us; speedup vs baseline: 1.3500x; 1.3500x over previous
//
#include <hip/hip_runtime.h>

typedef __bf16 bf16;
typedef __bf16 bf16x4 __attribute__((ext_vector_type(4)));
typedef __bf16 bf16x8 __attribute__((ext_vector_type(8)));
typedef float  f32x4  __attribute__((ext_vector_type(4)));

static constexpr int kC   = 1024;
static constexpr int kT   = 1024;
static constexpr int kB   = 4;
static constexpr int kH   = 16;
static constexpr int kHD  = 64;
static constexpr int kL   = 4;
static constexpr int kFF  = 100;
static constexpr int kFFP = 128;
static constexpr int kM   = kB * kT;

__device__ __forceinline__ void gload16(const bf16* g, bf16* l)
{
    __builtin_amdgcn_global_load_lds(
        (const __attribute__((address_space(1))) void*)g,
        (__attribute__((address_space(3))) void*)l, 16, 0, 0);
}

__device__ __forceinline__ unsigned bpack(float a, float b)
{
    bf16 x = (bf16)a, y = (bf16)b;
    unsigned short ux = __builtin_bit_cast(unsigned short, x);
    unsigned short uy = __builtin_bit_cast(unsigned short, y);
    return (unsigned)ux | ((unsigned)uy << 16);
}
__device__ __forceinline__ float blo(unsigned u) { return __builtin_bit_cast(float, u << 16); }
__device__ __forceinline__ float bhi(unsigned u) { return __builtin_bit_cast(float, u & 0xffff0000u); }

// ---------------------------------------------------------------------------
// One-shot prep: all weight transposes/converts + bias pack + pooled zero.
// ---------------------------------------------------------------------------
__global__ __launch_bounds__(256)
void prep_kernel(const float* __restrict__ Wq, const float* __restrict__ Wk,
                 const float* __restrict__ Wv, const float* __restrict__ Wo,
                 const float* __restrict__ W1, const float* __restrict__ W2,
                 const float* __restrict__ bq, const float* __restrict__ bk,
                 const float* __restrict__ bv,
                 bf16* __restrict__ WQKVT, bf16* __restrict__ WOT,
                 bf16* __restrict__ W1T, bf16* __restrict__ W2T,
                 float* __restrict__ BQKV, float* __restrict__ pooled)
{
    __shared__ float tile[32][33];
    const int bid = blockIdx.x, tid = threadIdx.x;
    const float* src; bf16* dst; int K, N, KP, NP, bx, by;
    if (bid < 12288) {
        const int slab = bid >> 10, within = bid & 1023;
        const int l = slab / 3, which = slab % 3;
        const float* W = (which == 0) ? Wq : (which == 1) ? Wk : Wv;
        src = W + (long)l * kC * kC;
        dst = WQKVT + (long)l * 3 * kC * kC + (long)which * kC * kC;
        K = N = KP = NP = kC; bx = within & 31; by = within >> 5;
    } else if (bid < 16384) {
        const int t = bid - 12288, z = t >> 10, within = t & 1023;
        src = Wo + (long)z * kC * kC; dst = WOT + (long)z * kC * kC;
        K = N = KP = NP = kC; bx = within & 31; by = within >> 5;
    } else if (bid < 16896) {
        const int t = bid - 16384, z = t >> 7, within = t & 127;
        src = W1 + (long)z * kC * kFF; dst = W1T + (long)z * kFFP * kC;
        K = kC; N = kFF; KP = kC; NP = kFFP; bx = within & 3; by = within >> 2;
    } else if (bid < 17408) {
        const int t = bid - 16896, z = t >> 7, within = t & 127;
        src = W2 + (long)z * kFF * kC; dst = W2T + (long)z * kC * kFFP;
        K = kFF; N = kC; KP = kFFP; NP = kC; bx = within & 31; by = within >> 5;
    } else if (bid < 17456) {
        const int gid = (bid - 17408) * 256 + tid;
        const int l = gid / (3 * kC), wq = (gid / kC) % 3, c = gid & (kC - 1);
        const float* s = (wq == 0) ? bq : (wq == 1) ? bk : bv;
        BQKV[gid] = s[l * kC + c];
        return;
    } else {
        const int i = (bid - 17456) * 256 + tid;
        if (i < kB * kC) pooled[i] = 0.f;
        return;
    }
    const int n0 = bx * 32, k0 = by * 32;
    const int tx = tid & 31, ty = tid >> 5;
#pragma unroll
    for (int i = 0; i < 4; ++i) {
        int k = k0 + ty + i * 8, n = n0 + tx;
        tile[ty + i * 8][tx] = (k < K && n < N) ? src[(long)k * N + n] : 0.f;
    }
    __syncthreads();
#pragma unroll
    for (int i = 0; i < 4; ++i) {
        int n = n0 + ty + i * 8, k = k0 + tx;
        if (n < NP && k < KP) dst[(long)n * KP + k] = (bf16)tile[tx][ty + i * 8];
    }
}

__global__ __launch_bounds__(256)
void embed_kernel(const int* __restrict__ idx, const float* __restrict__ tok,
                  const float* __restrict__ pos, float* __restrict__ x)
{
    const int m = blockIdx.x;
    const int c = threadIdx.x * 4;
    const int t = m & (kT - 1);
    const long tk = (long)idx[m] * kC;
    float4 a = *(const float4*)&tok[tk + c];
    float4 b = *(const float4*)&pos[(long)t * kC + c];
    float4 o; o.x = a.x + b.x; o.y = a.y + b.y; o.z = a.z + b.z; o.w = a.w + b.w;
    *(float4*)&x[(long)m * kC + c] = o;
}

__global__ __launch_bounds__(256)
void ln_kernel(const float* __restrict__ x, const float* __restrict__ g,
               const float* __restrict__ be, bf16* __restrict__ ob)
{
    __shared__ float red[8];
    const long row = blockIdx.x;
    const int tid = threadIdx.x, lane = tid & 63, wv = tid >> 6;
    const float4 v = *(const float4*)&x[row * kC + tid * 4];
    float s = v.x + v.y + v.z + v.w;
    float s2 = v.x * v.x + v.y * v.y + v.z * v.z + v.w * v.w;
#pragma unroll
    for (int o = 32; o > 0; o >>= 1) { s += __shfl_down(s, o); s2 += __shfl_down(s2, o); }
    if (!lane) { red[wv] = s; red[4 + wv] = s2; }
    __syncthreads();
    s  = red[0] + red[1] + red[2] + red[3];
    s2 = red[4] + red[5] + red[6] + red[7];
    const float mean = s * (1.f / kC);
    const float var  = s2 * (1.f / kC) - mean * mean;
    const float rstd = rsqrtf(var + 1e-5f);
    const float4 gg = *(const float4*)&g[tid * 4];
    const float4 bb = *(const float4*)&be[tid * 4];
    bf16x4 o;
    o[0] = (bf16)((v.x - mean) * rstd * gg.x + bb.x);
    o[1] = (bf16)((v.y - mean) * rstd * gg.y + bb.y);
    o[2] = (bf16)((v.z - mean) * rstd * gg.z + bb.z);
    o[3] = (bf16)((v.w - mean) * rstd * gg.w + bb.w);
    *(bf16x4*)&ob[row * kC + tid * 4] = o;
}

// ---------------------------------------------------------------------------
// MFMA GEMM: C = A * B^T.  GL=1: global_load_lds staging (BM/BN mult of 32).
// MODE 0: QKV (z=0 q*0.125*log2e -> [B,H,T,HD]; z=1 k; z=2 v -> VT)
// MODE 4: resid += acc + bias
// ---------------------------------------------------------------------------
template<int WAVES_M, int WAVES_N, int AI, int BJ, int MODE, int GL>
__global__ __launch_bounds__(256)
void gemm_bf16(const bf16* __restrict__ Ag, long strideA,
               const bf16* __restrict__ Bg, long strideB,
               const float* __restrict__ bias, int strideBias,
               bf16* __restrict__ outb, long strideOut,
               float* __restrict__ resid,
               int N, int K, int lda, int ldb)
{
    constexpr int BM = WAVES_M * AI * 16;
    constexpr int BN = WAVES_N * BJ * 16;
    constexpr int BK = 64;
    constexpr int LK = GL ? BK : (BK + 8);
    __shared__ __align__(16) bf16 As[BM * LK];
    __shared__ __align__(16) bf16 Bs[BN * LK];
    const int tid = threadIdx.x, lane = tid & 63, wv = tid >> 6;
    const int wm = wv / WAVES_N, wn = wv % WAVES_N;
    const int lr = lane & 15, lg = lane >> 4;
    const int z = blockIdx.z;
    const bf16* A = Ag + (long)z * strideA;
    const bf16* B = Bg + (long)z * strideB;
    const float* bi = bias ? bias + (long)z * strideBias : nullptr;
    const int m0 = blockIdx.y * BM, n0 = blockIdx.x * BN;

    f32x4 acc[AI][BJ];
#pragma unroll
    for (int i = 0; i < AI; ++i)
#pragma unroll
        for (int j = 0; j < BJ; ++j) acc[i][j] = (f32x4){0.f, 0.f, 0.f, 0.f};

    for (int k0 = 0; k0 < K; k0 += BK) {
        if constexpr (GL) {
            static_assert((BM % 32) == 0 && (BN % 32) == 0, "GL tile multiple of 32");
            const int sr  = lane >> 3;
            const int gcb = (lane & 7) ^ sr;
            constexpr int ARW = BM / 4;
            constexpr int BRW = BN / 4;
#pragma unroll
            for (int p = 0; p < BM / 32; ++p)
                gload16(A + (long)(m0 + wv * ARW + p * 8 + sr) * lda + k0 + gcb * 8,
                        &As[(wv * ARW + p * 8) * BK]);
#pragma unroll
            for (int p = 0; p < BN / 32; ++p)
                gload16(B + (long)(n0 + wv * BRW + p * 8 + sr) * ldb + k0 + gcb * 8,
                        &Bs[(wv * BRW + p * 8) * BK]);
        } else {
            constexpr int AP = (BM * BK) / (256 * 8);
#pragma unroll
            for (int p = 0; p < AP; ++p) {
                int r = p * 32 + (tid >> 3), c = (tid & 7) * 8;
                *(uint4*)&As[r * LK + c] = *(const uint4*)&A[(long)(m0 + r) * lda + k0 + c];
            }
            constexpr int BP = (BN * BK) / (256 * 8);
#pragma unroll
            for (int p = 0; p < BP; ++p) {
                int r = p * 32 + (tid >> 3), c = (tid & 7) * 8;
                *(uint4*)&Bs[r * LK + c] = *(const uint4*)&B[(long)(n0 + r) * ldb + k0 + c];
            }
        }
        __syncthreads();
#pragma unroll
        for (int kk = 0; kk < 2; ++kk) {
            bf16x8 af[AI], bfv[BJ];
#pragma unroll
            for (int i = 0; i < AI; ++i) {
                const int r = wm * AI * 16 + i * 16 + lr;
                const int c = GL ? (((kk * 4 + lg) ^ (lr & 7)) * 8) : (kk * 32 + lg * 8);
                af[i] = *(const bf16x8*)&As[r * LK + c];
            }
#pragma unroll
            for (int j = 0; j < BJ; ++j) {
                const int r = wn * BJ * 16 + j * 16 + lr;
                const int c = GL ? (((kk * 4 + lg) ^ (lr & 7)) * 8) : (kk * 32 + lg * 8);
                bfv[j] = *(const bf16x8*)&Bs[r * LK + c];
            }
#pragma unroll
            for (int i = 0; i < AI; ++i)
#pragma unroll
                for (int j = 0; j < BJ; ++j)
                    acc[i][j] = __builtin_amdgcn_mfma_f32_16x16x32_bf16(af[i], bfv[j], acc[i][j], 0, 0, 0);
        }
        __syncthreads();
    }

#pragma unroll
    for (int i = 0; i < AI; ++i)
#pragma unroll
        for (int j = 0; j < BJ; ++j)
#pragma unroll
            for (int rr = 0; rr < 4; ++rr) {
                const int grow = m0 + wm * AI * 16 + i * 16 + lg * 4 + rr;
                const int gcol = n0 + wn * BJ * 16 + j * 16 + lr;
                float v = acc[i][j][rr];
                if constexpr (MODE == 0) {
                    v += bi[gcol];
                    if (z == 0) v *= 0.125f * 1.44269504f;  // scale * log2(e)
                    const int b = grow >> 10, t = grow & (kT - 1);
                    const int hh = gcol >> 6, hd = gcol & 63;
                    long o = (long)z * strideOut;
                    if (z == 2) o += (((long)b * kH + hh) * kHD + hd) * kT + t;  // VT
                    else        o += (((long)b * kH + hh) * kT + t) * kHD + hd;  // Q/K
                    outb[o] = (bf16)v;
                } else {
                    v += bi[gcol];
                    resid[(long)grow * N + gcol] += v;
                }
            }
}

// ---------------------------------------------------------------------------
// Fused FF: ln2 + FF1(relu) + FF2(+=X), one block per 16 rows, 4 waves.
// ---------------------------------------------------------------------------
__global__ __launch_bounds__(256, 2)
void ff_fused(float* __restrict__ X, const float* __restrict__ g,
              const float* __restrict__ be,
              const bf16* __restrict__ W1T_, const float* __restrict__ b1_,
              const bf16* __restrict__ W2T_, const float* __restrict__ b2_)
{
    __shared__ __align__(16) bf16 Hs[16 * kC];
    __shared__ __align__(16) bf16 F1s[16 * kFFP];
    const int tid = threadIdx.x, lane = tid & 63, w = tid >> 6;
    const int lr = lane & 15, lg = lane >> 4;
    const int r0 = blockIdx.x * 16;

    {
        const int row = tid >> 4, c16 = tid & 15;
        float4 xv[16];
        float s1 = 0.f, s2 = 0.f;
#pragma unroll
        for (int p = 0; p < 8; ++p) {
            const float* base = &X[(long)(r0 + row) * kC + p * 128 + c16 * 8];
            xv[2 * p]     = *(const float4*)base;
            xv[2 * p + 1] = *(const float4*)(base + 4);
#pragma unroll
            for (int e = 0; e < 4; ++e) {
                float a0 = ((const float*)&xv[2 * p])[e], a1 = ((const float*)&xv[2 * p + 1])[e];
                s1 += a0 + a1; s2 += a0 * a0 + a1 * a1;
            }
        }
#pragma unroll
        for (int off = 1; off < 16; off <<= 1) { s1 += __shfl_xor(s1, off); s2 += __shfl_xor(s2, off); }
        const float mean = s1 * (1.f / kC);
        const float rstd = rsqrtf(s2 * (1.f / kC) - mean * mean + 1e-5f);
#pragma unroll
        for (int p = 0; p < 8; ++p) {
            const int c0 = p * 128 + c16 * 8;
            float4 g0 = *(const float4*)&g[c0],  g1 = *(const float4*)&g[c0 + 4];
            float4 b0 = *(const float4*)&be[c0], b1v = *(const float4*)&be[c0 + 4];
            float h[8];
#pragma unroll
            for (int e = 0; e < 4; ++e) {
                h[e]     = (((const float*)&xv[2 * p])[e]     - mean) * rstd * ((const float*)&g0)[e] + ((const float*)&b0)[e];
                h[4 + e] = (((const float*)&xv[2 * p + 1])[e] - mean) * rstd * ((const float*)&g1)[e] + ((const float*)&b1v)[e];
            }
            uint4 hv;
            hv.x = bpack(h[0], h[1]); hv.y = bpack(h[2], h[3]);
            hv.z = bpack(h[4], h[5]); hv.w = bpack(h[6], h[7]);
            const int cb = c16 + p * 16;
            *(uint4*)&Hs[row * kC + ((cb ^ (row & 7)) << 3)] = hv;
        }
    }
    __syncthreads();

    {
        f32x4 accA[2], accB[2];
#pragma unroll
        for (int j = 0; j < 2; ++j) { accA[j] = (f32x4){0,0,0,0}; accB[j] = (f32x4){0,0,0,0}; }
        for (int k0 = 0; k0 < kC; k0 += 64) {
            const bf16x8 a0 = *(const bf16x8*)&Hs[lr * kC + ((((k0 >> 3) + 0 * 4 + lg) ^ (lr & 7)) << 3)];
            const bf16x8 a1 = *(const bf16x8*)&Hs[lr * kC + ((((k0 >> 3) + 1 * 4 + lg) ^ (lr & 7)) << 3)];
#pragma unroll
            for (int j = 0; j < 2; ++j) {
                const bf16x8 b0 = *(const bf16x8*)&W1T_[(long)(w * 32 + j * 16 + lr) * kC + k0 + 0 * 32 + lg * 8];
                const bf16x8 b1 = *(const bf16x8*)&W1T_[(long)(w * 32 + j * 16 + lr) * kC + k0 + 1 * 32 + lg * 8];
                accA[j] = __builtin_amdgcn_mfma_f32_16x16x32_bf16(a0, b0, accA[j], 0, 0, 0);
                accB[j] = __builtin_amdgcn_mfma_f32_16x16x32_bf16(a1, b1, accB[j], 0, 0, 0);
            }
        }
#pragma unroll
        for (int j = 0; j < 2; ++j)
#pragma unroll
            for (int rr = 0; rr < 4; ++rr) {
                const int row = lg * 4 + rr, col = w * 32 + j * 16 + lr;
                float v = accA[j][rr] + accB[j][rr] + (col < kFF ? b1_[col] : 0.f);
                F1s[row * kFFP + (((col >> 3) ^ (row & 7)) << 3) + (col & 7)] = (bf16)fmaxf(v, 0.f);
            }
    }
    __syncthreads();

    for (int nc = 0; nc < 8; ++nc) {
        f32x4 acc[2];
        acc[0] = (f32x4){0.f, 0.f, 0.f, 0.f};
        acc[1] = (f32x4){0.f, 0.f, 0.f, 0.f};
#pragma unroll
        for (int kk = 0; kk < 4; ++kk) {
            const bf16x8 a = *(const bf16x8*)&F1s[lr * kFFP + (((kk * 4 + lg) ^ (lr & 7)) << 3)];
#pragma unroll
            for (int j = 0; j < 2; ++j) {
                const bf16x8 bv = *(const bf16x8*)&W2T_[(long)(nc * 128 + w * 32 + j * 16 + lr) * kFFP + kk * 32 + lg * 8];
                acc[j] = __builtin_amdgcn_mfma_f32_16x16x32_bf16(a, bv, acc[j], 0, 0, 0);
            }
        }
#pragma unroll
        for (int j = 0; j < 2; ++j)
#pragma unroll
            for (int rr = 0; rr < 4; ++rr) {
                const int row = r0 + lg * 4 + rr, col = nc * 128 + w * 32 + j * 16 + lr;
                X[(long)row * kC + col] += acc[j][rr] + b2_[col];
            }
    }
}

// ---------------------------------------------------------------------------
// Fused attention v14 (REVERTED to R16 best): depth-2 REGISTER prefetch.
// Staging: global->reg issued 2 tiles ahead; reg->LDS ds_write 1 tile ahead
// (thread writes the exact 16B global_load_lds would have -> identical
// wave-private layout). Compiler emits counted vmcnt waits for the reg
// dependency, so the per-tile latency gap is covered by 2 full phases.
// Per-tile barrier remains lgkm-only (Ps cross-wave visibility).
// LDS: K 2x8K + VT 2x8K + Ps 32K = 64 KB -> 2 blocks/CU.
// ---------------------------------------------------------------------------
__global__ __launch_bounds__(256, 2)
void attn_fused(const bf16* __restrict__ Qg, const bf16* __restrict__ Kg,
                const bf16* __restrict__ VTg, bf16* __restrict__ yg,
                float* __restrict__ attm)
{
    __shared__ __align__(16) bf16 SH[32768];   // 64 KB total
    bf16* Klds = SH;                           // 2 bufs x [64][64]
    bf16* Vlds = SH + 8192;                    // 2 bufs x [64][64]
    bf16* Ps   = SH + 16384;                   // [16][1024] swizzled E
    __shared__ __align__(16) float reds[16][4];
    __shared__ float invs[16];
    const int tid = threadIdx.x, lane = tid & 63, w = tid >> 6;   // w 0..3
    const int lr = lane & 15, lg = lane >> 4;
    const int bid = blockIdx.x, r_ = bid >> 3;
    const int h = ((bid & 7) << 1) | (r_ & 1);    // XCD-local head
    const int q0 = (r_ >> 1) * 16;

    const int sr  = lane >> 3;                 // staging row within 8-row chunk
    const int gcb = (lane & 7) ^ sr;           // inverse-swizzled src col-block
    const int loB = (lg & 1) * 4;
    const int rowb = w * 16 + sr;
    const int ldK0 = (w * 16) * 64, ldK1 = (w * 16 + 8) * 64;
    const int wr8 = lane * 8;                  // thread's 16B slot within chunk

    unsigned am_[16][2];                       // attm acc (q=lr), packed bf16x2
#pragma unroll
    for (int j = 0; j < 16; ++j) { am_[j][0] = 0u; am_[j][1] = 0u; }

    for (int b = 0; b < kB; ++b) {
        const long bh = (long)b * kH + h;
        const bf16* Qb = Qg + (bh * kT + q0) * kHD;
        const bf16* Kb = Kg + bh * kT * kHD;
        const bf16* Vb = VTg + bh * (long)kHD * kT;

        // Q fragments (tiny, L2-hot)
        const bf16x8 qf0 = *(const bf16x8*)&Qb[lr * kHD + lg * 8];
        const bf16x8 qf1 = *(const bf16x8*)&Qb[lr * kHD + 32 + lg * 8];

        // ---- warmup: reg-load tiles 0 (set A) and 1 (set B); write tile 0
        uint4 kA0 = *(const uint4*)(Kb + (rowb)     * kHD + gcb * 8);
        uint4 kA1 = *(const uint4*)(Kb + (rowb + 8) * kHD + gcb * 8);
        uint4 vA0 = *(const uint4*)(Vb + (long)(rowb)     * kT + gcb * 8);
        uint4 vA1 = *(const uint4*)(Vb + (long)(rowb + 8) * kT + gcb * 8);
        uint4 kB0 = *(const uint4*)(Kb + (64 + rowb)     * kHD + gcb * 8);
        uint4 kB1 = *(const uint4*)(Kb + (64 + rowb + 8) * kHD + gcb * 8);
        uint4 vB0 = *(const uint4*)(Vb + (long)(rowb)     * kT + 64 + gcb * 8);
        uint4 vB1 = *(const uint4*)(Vb + (long)(rowb + 8) * kT + 64 + gcb * 8);
        *(uint4*)&Klds[ldK0 + wr8] = kA0;
        *(uint4*)&Klds[ldK1 + wr8] = kA1;
        *(uint4*)&Vlds[ldK0 + wr8] = vA0;
        *(uint4*)&Vlds[ldK1 + wr8] = vA1;

        float s = 0.f;
        f32x4 y0 = (f32x4){0.f, 0.f, 0.f, 0.f};
        f32x4 y1 = (f32x4){0.f, 0.f, 0.f, 0.f};

#pragma unroll
        for (int kt = 0; kt < 16; ++kt) {
            const int cur = (kt & 1) * 4096;
            const int nxt = 4096 - cur;
            // 1) issue reg loads for tile kt+2 into the set freed last iter
            if (kt < 14) {
                const int kn = (kt + 2) * 64;
                if ((kt & 1) == 0) {
                    kA0 = *(const uint4*)(Kb + (kn + rowb)     * kHD + gcb * 8);
                    kA1 = *(const uint4*)(Kb + (kn + rowb + 8) * kHD + gcb * 8);
                    vA0 = *(const uint4*)(Vb + (long)(rowb)     * kT + kn + gcb * 8);
                    vA1 = *(const uint4*)(Vb + (long)(rowb + 8) * kT + kn + gcb * 8);
                } else {
                    kB0 = *(const uint4*)(Kb + (kn + rowb)     * kHD + gcb * 8);
                    kB1 = *(const uint4*)(Kb + (kn + rowb + 8) * kHD + gcb * 8);
                    vB0 = *(const uint4*)(Vb + (long)(rowb)     * kT + kn + gcb * 8);
                    vB1 = *(const uint4*)(Vb + (long)(rowb + 8) * kT + kn + gcb * 8);
                }
            }

            // 2) QK^T from buf[cur] (own-wave K rows)
            const int krow = w * 16 + lr;
            const bf16x8 kf0 = *(const bf16x8*)&Klds[cur + krow * 64 + (((0 + lg) ^ (lr & 7)) << 3)];
            const bf16x8 kf1 = *(const bf16x8*)&Klds[cur + krow * 64 + (((4 + lg) ^ (lr & 7)) << 3)];
            f32x4 a = (f32x4){0.f, 0.f, 0.f, 0.f};
            a = __builtin_amdgcn_mfma_f32_16x16x32_bf16(kf0, qf0, a, 0, 0, 0);
            a = __builtin_amdgcn_mfma_f32_16x16x32_bf16(kf1, qf1, a, 0, 0, 0);
            const float e0 = exp2f(a[0]), e1 = exp2f(a[1]);
            const float e2 = exp2f(a[2]), e3 = exp2f(a[3]);
            s += (e0 + e1) + (e2 + e3);
            const int tb = kt * 8 + w * 2 + (lg >> 1);
            uint2 pk; pk.x = bpack(e0, e1); pk.y = bpack(e2, e3);
            *(uint2*)&Ps[lr * kT + ((tb ^ (lr & 7)) << 3) + loB] = pk;

            // 3) write tile kt+1 regs -> buf[nxt] (compiler inserts counted vmcnt)
            if (kt < 15) {
                if ((kt & 1) == 0) {
                    *(uint4*)&Klds[nxt + ldK0 + wr8] = kB0;
                    *(uint4*)&Klds[nxt + ldK1 + wr8] = kB1;
                    *(uint4*)&Vlds[nxt + ldK0 + wr8] = vB0;
                    *(uint4*)&Vlds[nxt + ldK1 + wr8] = vB1;
                } else {
                    *(uint4*)&Klds[nxt + ldK0 + wr8] = kA0;
                    *(uint4*)&Klds[nxt + ldK1 + wr8] = kA1;
                    *(uint4*)&Vlds[nxt + ldK0 + wr8] = vA0;
                    *(uint4*)&Vlds[nxt + ldK1 + wr8] = vA1;
                }
            }

            // 4) single barrier: E cross-wave visible (lgkm only)
            asm volatile("s_waitcnt lgkmcnt(0)" ::: "memory");
            __builtin_amdgcn_s_barrier();
            __builtin_amdgcn_sched_barrier(0);

            // 5) PV from buf[cur] (own-wave V rows) + Ps; dual chains
            const int vrow = w * 16 + lr;
            const bf16x8 a0 = *(const bf16x8*)&Ps[lr * kT + (((kt * 8 + 0 + lg) ^ (lr & 7)) << 3)];
            const bf16x8 v0 = *(const bf16x8*)&Vlds[cur + vrow * 64 + (((0 + lg) ^ (lr & 7)) << 3)];
            const bf16x8 a1 = *(const bf16x8*)&Ps[lr * kT + (((kt * 8 + 4 + lg) ^ (lr & 7)) << 3)];
            const bf16x8 v1 = *(const bf16x8*)&Vlds[cur + vrow * 64 + (((4 + lg) ^ (lr & 7)) << 3)];
            y0 = __builtin_amdgcn_mfma_f32_16x16x32_bf16(a0, v0, y0, 0, 0, 0);
            y1 = __builtin_amdgcn_mfma_f32_16x16x32_bf16(a1, v1, y1, 0, 0, 0);
        }

        // row sums -> inv
        s += __shfl_xor(s, 16);
        s += __shfl_xor(s, 32);
        if (lane < 16) reds[lane][w] = s;
        asm volatile("s_waitcnt lgkmcnt(0)" ::: "memory");
        __builtin_amdgcn_s_barrier();
        __builtin_amdgcn_sched_barrier(0);
        float4 rv = *(const float4*)&reds[lr][0];
        const float inv = __builtin_amdgcn_rcpf((rv.x + rv.y) + (rv.z + rv.w));
        const float iv4 = inv * 0.25f;
        if (lane < 16) invs[lane] = inv;

        // am += E * inv/4  (read back own-thread E dwords)
#pragma unroll
        for (int kt = 0; kt < 16; ++kt) {
            const int tb = kt * 8 + w * 2 + (lg >> 1);
            uint2 e2v = *(const uint2*)&Ps[lr * kT + ((tb ^ (lr & 7)) << 3) + loB];
#pragma unroll
            for (int d = 0; d < 2; ++d) {
                unsigned ev = d ? e2v.y : e2v.x;
                unsigned av = am_[kt][d];
                float n0 = blo(av) + blo(ev) * iv4;
                float n1 = bhi(av) + bhi(ev) * iv4;
                am_[kt][d] = bpack(n0, n1);
            }
        }

        // y write (row q = lg*4+rr, col d = w*16+lr)
#pragma unroll
        for (int rr = 0; rr < 4; ++rr) {
            const float iv = invs[lg * 4 + rr];
            yg[((long)b * kT + q0 + lg * 4 + rr) * kC + h * kHD + w * 16 + lr]
                = (bf16)((y0[rr] + y1[rr]) * iv);
        }
    }

    __syncthreads();   // all Ps/K/V reads done before fp32 reuse of SH
    // attm epilogue: stage [16][1024] fp32 in SH, stream out coalesced
    float* amf = (float*)SH;
#pragma unroll
    for (int kt = 0; kt < 16; ++kt)
#pragma unroll
        for (int d = 0; d < 2; ++d) {
            unsigned av = am_[kt][d];
            const int col = kt * 64 + w * 16 + lg * 4 + 2 * d;
            amf[lr * kT + col]     = blo(av);
            amf[lr * kT + col + 1] = bhi(av);
        }
    __syncthreads();
#pragma unroll
    for (int p = 0; p < 16; ++p) {
        const int f = p * 256 + tid;              // 4096 float4s
        const int row = f >> 8, c4 = f & 255;
        float4 v = *(const float4*)&amf[row * kT + c4 * 4];
        *(float4*)&attm[((long)h * kT + q0 + row) * kT + c4 * 4] = v;
    }
}

// pooled[b][c] = mean_t hb[b,t,c]  (bf16 input)
__global__ __launch_bounds__(256)
void pool_kernel(const bf16* __restrict__ hb, float* __restrict__ pooled)
{
    const int c = blockIdx.x * 256 + threadIdx.x;
    const int b = blockIdx.y;
    const int t0 = blockIdx.z * 128;
    float s = 0.f;
    for (int t = t0; t < t0 + 128; ++t) s += (float)hb[((long)b * kT + t) * kC + c];
    atomicAdd(&pooled[b * kC + c], s * (1.f / kT));
}

// ---------------------------------------------------------------------------
extern "C" void kernel_launch(void* const* d_in, const int* in_sizes, int n_in,
                              void* d_out, int out_size, void* d_ws, size_t ws_size,
                              hipStream_t stream)
{
    const int*   idx  = (const int*)d_in[0];
    const float* tok  = (const float*)d_in[1];
    const float* pos  = (const float*)d_in[2];
    const float* Wq   = (const float*)d_in[3];
    const float* bq   = (const float*)d_in[4];
    const float* Wk   = (const float*)d_in[5];
    const float* bk   = (const float*)d_in[6];
    const float* Wv   = (const float*)d_in[7];
    const float* bv   = (const float*)d_in[8];
    const float* Wo   = (const float*)d_in[9];
    const float* bo   = (const float*)d_in[10];
    const float* ln1w = (const float*)d_in[11];
    const float* ln1b = (const float*)d_in[12];
    const float* ln2w = (const float*)d_in[13];
    const float* ln2b = (const float*)d_in[14];
    const float* W1   = (const float*)d_in[15];
    const float* b1   = (const float*)d_in[16];
    const float* W2   = (const float*)d_in[17];
    const float* b2   = (const float*)d_in[18];
    const float* lnfw = (const float*)d_in[19];
    const float* lnfb = (const float*)d_in[20];

    char* ws = (char*)d_ws;
    long off = 0;
    auto alloc = [&](long bytes) { char* p = ws + off; off += (bytes + 255) & ~255L; return p; };
    bf16*  WQKVT = (bf16*)alloc((long)kL * 3 * kC * kC * 2);
    bf16*  WOT   = (bf16*)alloc((long)kL * kC * kC * 2);
    bf16*  W1T   = (bf16*)alloc((long)kL * kFFP * kC * 2);
    bf16*  W2T   = (bf16*)alloc((long)kL * kC * kFFP * 2);
    float* BQKV  = (float*)alloc((long)kL * 3 * kC * 4);
    float* X     = (float*)alloc((long)kM * kC * 4);
    bf16*  Hbuf  = (bf16*)alloc((long)kM * kC * 2);
    bf16*  QKV   = (bf16*)alloc(3L * kM * kC * 2);
    bf16*  Y     = (bf16*)alloc((long)kM * kC * 2);

    float* pooled = (float*)d_out;
    float* attm_base = pooled + kB * kC;

    prep_kernel<<<17472, 256, 0, stream>>>(Wq, Wk, Wv, Wo, W1, W2, bq, bk, bv,
                                           WQKVT, WOT, W1T, W2T, BQKV, pooled);
    embed_kernel<<<kM, 256, 0, stream>>>(idx, tok, pos, X);

    for (int l = 0; l < kL; ++l) {
        ln_kernel<<<kM, 256, 0, stream>>>(X, ln1w + l * kC, ln1b + l * kC, Hbuf);
        gemm_bf16<2, 2, 4, 4, 0, 1><<<dim3(8, 32, 3), 256, 0, stream>>>(
            Hbuf, 0L, WQKVT + (long)l * 3 * kC * kC, (long)kC * kC,
            BQKV + l * 3 * kC, kC, QKV, (long)kM * kC, nullptr,
            kC, kC, kC, kC);
        attn_fused<<<dim3(1024), 256, 0, stream>>>(
            QKV, QKV + (long)kM * kC, QKV + 2L * kM * kC, Y,
            attm_base + (long)l * kH * kT * kT);
        gemm_bf16<2, 2, 4, 4, 4, 1><<<dim3(8, 32, 1), 256, 0, stream>>>(
            Y, 0L, WOT + (long)l * kC * kC, 0L, bo + l * kC, 0,
            nullptr, 0L, X, kC, kC, kC, kC);
        ff_fused<<<256, 256, 0, stream>>>(X, ln2w + l * kC, ln2b + l * kC,
                                          W1T + (long)l * kFFP * kC, b1 + l * kFF,
                                          W2T + (long)l * kC * kFFP, b2 + l * kC);
    }
    ln_kernel<<<kM, 256, 0, stream>>>(X, lnfw, lnfb, Hbuf);
    pool_kernel<<<dim3(4, kB, 8), 256, 0, stream>>>(Hbuf, pooled);
}

// Round 19
// 795.935 us; speedup vs baseline: 1.3863x; 1.0269x over previous
//
#include <hip/hip_runtime.h>

typedef __bf16 bf16;
typedef __bf16 bf16x4 __attribute__((ext_vector_type(4)));
typedef __bf16 bf16x8 __attribute__((ext_vector_type(8)));
typedef float  f32x4  __attribute__((ext_vector_type(4)));

static constexpr int kC   = 1024;
static constexpr int kT   = 1024;
static constexpr int kB   = 4;
static constexpr int kH   = 16;
static constexpr int kHD  = 64;
static constexpr int kL   = 4;
static constexpr int kFF  = 100;
static constexpr int kFFP = 128;
static constexpr int kM   = kB * kT;

__device__ __forceinline__ void gload16(const bf16* g, bf16* l)
{
    __builtin_amdgcn_global_load_lds(
        (const __attribute__((address_space(1))) void*)g,
        (__attribute__((address_space(3))) void*)l, 16, 0, 0);
}

__device__ __forceinline__ unsigned bpack(float a, float b)
{
    bf16 x = (bf16)a, y = (bf16)b;
    unsigned short ux = __builtin_bit_cast(unsigned short, x);
    unsigned short uy = __builtin_bit_cast(unsigned short, y);
    return (unsigned)ux | ((unsigned)uy << 16);
}
__device__ __forceinline__ float blo(unsigned u) { return __builtin_bit_cast(float, u << 16); }
__device__ __forceinline__ float bhi(unsigned u) { return __builtin_bit_cast(float, u & 0xffff0000u); }

// ---------------------------------------------------------------------------
// One-shot prep: all weight transposes/converts + bias pack + pooled zero.
// ---------------------------------------------------------------------------
__global__ __launch_bounds__(256)
void prep_kernel(const float* __restrict__ Wq, const float* __restrict__ Wk,
                 const float* __restrict__ Wv, const float* __restrict__ Wo,
                 const float* __restrict__ W1, const float* __restrict__ W2,
                 const float* __restrict__ bq, const float* __restrict__ bk,
                 const float* __restrict__ bv,
                 bf16* __restrict__ WQKVT, bf16* __restrict__ WOT,
                 bf16* __restrict__ W1T, bf16* __restrict__ W2T,
                 float* __restrict__ BQKV, float* __restrict__ pooled)
{
    __shared__ float tile[32][33];
    const int bid = blockIdx.x, tid = threadIdx.x;
    const float* src; bf16* dst; int K, N, KP, NP, bx, by;
    if (bid < 12288) {
        const int slab = bid >> 10, within = bid & 1023;
        const int l = slab / 3, which = slab % 3;
        const float* W = (which == 0) ? Wq : (which == 1) ? Wk : Wv;
        src = W + (long)l * kC * kC;
        dst = WQKVT + (long)l * 3 * kC * kC + (long)which * kC * kC;
        K = N = KP = NP = kC; bx = within & 31; by = within >> 5;
    } else if (bid < 16384) {
        const int t = bid - 12288, z = t >> 10, within = t & 1023;
        src = Wo + (long)z * kC * kC; dst = WOT + (long)z * kC * kC;
        K = N = KP = NP = kC; bx = within & 31; by = within >> 5;
    } else if (bid < 16896) {
        const int t = bid - 16384, z = t >> 7, within = t & 127;
        src = W1 + (long)z * kC * kFF; dst = W1T + (long)z * kFFP * kC;
        K = kC; N = kFF; KP = kC; NP = kFFP; bx = within & 3; by = within >> 2;
    } else if (bid < 17408) {
        const int t = bid - 16896, z = t >> 7, within = t & 127;
        src = W2 + (long)z * kFF * kC; dst = W2T + (long)z * kC * kFFP;
        K = kFF; N = kC; KP = kFFP; NP = kC; bx = within & 31; by = within >> 5;
    } else if (bid < 17456) {
        const int gid = (bid - 17408) * 256 + tid;
        const int l = gid / (3 * kC), wq = (gid / kC) % 3, c = gid & (kC - 1);
        const float* s = (wq == 0) ? bq : (wq == 1) ? bk : bv;
        BQKV[gid] = s[l * kC + c];
        return;
    } else {
        const int i = (bid - 17456) * 256 + tid;
        if (i < kB * kC) pooled[i] = 0.f;
        return;
    }
    const int n0 = bx * 32, k0 = by * 32;
    const int tx = tid & 31, ty = tid >> 5;
#pragma unroll
    for (int i = 0; i < 4; ++i) {
        int k = k0 + ty + i * 8, n = n0 + tx;
        tile[ty + i * 8][tx] = (k < K && n < N) ? src[(long)k * N + n] : 0.f;
    }
    __syncthreads();
#pragma unroll
    for (int i = 0; i < 4; ++i) {
        int n = n0 + ty + i * 8, k = k0 + tx;
        if (n < NP && k < KP) dst[(long)n * KP + k] = (bf16)tile[tx][ty + i * 8];
    }
}

// embed + ln1(layer0) fused: x row -> X, then LayerNorm -> Hbuf (bf16)
__global__ __launch_bounds__(256)
void embed_kernel(const int* __restrict__ idx, const float* __restrict__ tok,
                  const float* __restrict__ pos, float* __restrict__ x,
                  const float* __restrict__ g, const float* __restrict__ be,
                  bf16* __restrict__ ob)
{
    __shared__ float red[8];
    const int m = blockIdx.x;
    const int tid = threadIdx.x, lane = tid & 63, wv = tid >> 6;
    const int c = tid * 4;
    const int t = m & (kT - 1);
    const long tk = (long)idx[m] * kC;
    float4 a = *(const float4*)&tok[tk + c];
    float4 b = *(const float4*)&pos[(long)t * kC + c];
    float4 v; v.x = a.x + b.x; v.y = a.y + b.y; v.z = a.z + b.z; v.w = a.w + b.w;
    *(float4*)&x[(long)m * kC + c] = v;

    float s = v.x + v.y + v.z + v.w;
    float s2 = v.x * v.x + v.y * v.y + v.z * v.z + v.w * v.w;
#pragma unroll
    for (int o = 32; o > 0; o >>= 1) { s += __shfl_down(s, o); s2 += __shfl_down(s2, o); }
    if (!lane) { red[wv] = s; red[4 + wv] = s2; }
    __syncthreads();
    s  = red[0] + red[1] + red[2] + red[3];
    s2 = red[4] + red[5] + red[6] + red[7];
    const float mean = s * (1.f / kC);
    const float rstd = rsqrtf(s2 * (1.f / kC) - mean * mean + 1e-5f);
    const float4 gg = *(const float4*)&g[c];
    const float4 bb = *(const float4*)&be[c];
    bf16x4 o;
    o[0] = (bf16)((v.x - mean) * rstd * gg.x + bb.x);
    o[1] = (bf16)((v.y - mean) * rstd * gg.y + bb.y);
    o[2] = (bf16)((v.z - mean) * rstd * gg.z + bb.z);
    o[3] = (bf16)((v.w - mean) * rstd * gg.w + bb.w);
    *(bf16x4*)&ob[(long)m * kC + c] = o;
}

// ---------------------------------------------------------------------------
// MFMA GEMM: C = A * B^T.  GL=1: global_load_lds staging (BM/BN mult of 32).
// MODE 0: QKV (z=0 q*0.125*log2e -> [B,H,T,HD]; z=1 k; z=2 v -> VT)
// MODE 4: resid += acc + bias
// ---------------------------------------------------------------------------
template<int WAVES_M, int WAVES_N, int AI, int BJ, int MODE, int GL>
__global__ __launch_bounds__(256)
void gemm_bf16(const bf16* __restrict__ Ag, long strideA,
               const bf16* __restrict__ Bg, long strideB,
               const float* __restrict__ bias, int strideBias,
               bf16* __restrict__ outb, long strideOut,
               float* __restrict__ resid,
               int N, int K, int lda, int ldb)
{
    constexpr int BM = WAVES_M * AI * 16;
    constexpr int BN = WAVES_N * BJ * 16;
    constexpr int BK = 64;
    constexpr int LK = GL ? BK : (BK + 8);
    __shared__ __align__(16) bf16 As[BM * LK];
    __shared__ __align__(16) bf16 Bs[BN * LK];
    const int tid = threadIdx.x, lane = tid & 63, wv = tid >> 6;
    const int wm = wv / WAVES_N, wn = wv % WAVES_N;
    const int lr = lane & 15, lg = lane >> 4;
    const int z = blockIdx.z;
    const bf16* A = Ag + (long)z * strideA;
    const bf16* B = Bg + (long)z * strideB;
    const float* bi = bias ? bias + (long)z * strideBias : nullptr;
    const int m0 = blockIdx.y * BM, n0 = blockIdx.x * BN;

    f32x4 acc[AI][BJ];
#pragma unroll
    for (int i = 0; i < AI; ++i)
#pragma unroll
        for (int j = 0; j < BJ; ++j) acc[i][j] = (f32x4){0.f, 0.f, 0.f, 0.f};

    for (int k0 = 0; k0 < K; k0 += BK) {
        if constexpr (GL) {
            static_assert((BM % 32) == 0 && (BN % 32) == 0, "GL tile multiple of 32");
            const int sr  = lane >> 3;
            const int gcb = (lane & 7) ^ sr;
            constexpr int ARW = BM / 4;
            constexpr int BRW = BN / 4;
#pragma unroll
            for (int p = 0; p < BM / 32; ++p)
                gload16(A + (long)(m0 + wv * ARW + p * 8 + sr) * lda + k0 + gcb * 8,
                        &As[(wv * ARW + p * 8) * BK]);
#pragma unroll
            for (int p = 0; p < BN / 32; ++p)
                gload16(B + (long)(n0 + wv * BRW + p * 8 + sr) * ldb + k0 + gcb * 8,
                        &Bs[(wv * BRW + p * 8) * BK]);
        } else {
            constexpr int AP = (BM * BK) / (256 * 8);
#pragma unroll
            for (int p = 0; p < AP; ++p) {
                int r = p * 32 + (tid >> 3), c = (tid & 7) * 8;
                *(uint4*)&As[r * LK + c] = *(const uint4*)&A[(long)(m0 + r) * lda + k0 + c];
            }
            constexpr int BP = (BN * BK) / (256 * 8);
#pragma unroll
            for (int p = 0; p < BP; ++p) {
                int r = p * 32 + (tid >> 3), c = (tid & 7) * 8;
                *(uint4*)&Bs[r * LK + c] = *(const uint4*)&B[(long)(n0 + r) * ldb + k0 + c];
            }
        }
        __syncthreads();
#pragma unroll
        for (int kk = 0; kk < 2; ++kk) {
            bf16x8 af[AI], bfv[BJ];
#pragma unroll
            for (int i = 0; i < AI; ++i) {
                const int r = wm * AI * 16 + i * 16 + lr;
                const int c = GL ? (((kk * 4 + lg) ^ (lr & 7)) * 8) : (kk * 32 + lg * 8);
                af[i] = *(const bf16x8*)&As[r * LK + c];
            }
#pragma unroll
            for (int j = 0; j < BJ; ++j) {
                const int r = wn * BJ * 16 + j * 16 + lr;
                const int c = GL ? (((kk * 4 + lg) ^ (lr & 7)) * 8) : (kk * 32 + lg * 8);
                bfv[j] = *(const bf16x8*)&Bs[r * LK + c];
            }
#pragma unroll
            for (int i = 0; i < AI; ++i)
#pragma unroll
                for (int j = 0; j < BJ; ++j)
                    acc[i][j] = __builtin_amdgcn_mfma_f32_16x16x32_bf16(af[i], bfv[j], acc[i][j], 0, 0, 0);
        }
        __syncthreads();
    }

#pragma unroll
    for (int i = 0; i < AI; ++i)
#pragma unroll
        for (int j = 0; j < BJ; ++j)
#pragma unroll
            for (int rr = 0; rr < 4; ++rr) {
                const int grow = m0 + wm * AI * 16 + i * 16 + lg * 4 + rr;
                const int gcol = n0 + wn * BJ * 16 + j * 16 + lr;
                float v = acc[i][j][rr];
                if constexpr (MODE == 0) {
                    v += bi[gcol];
                    if (z == 0) v *= 0.125f * 1.44269504f;  // scale * log2(e)
                    const int b = grow >> 10, t = grow & (kT - 1);
                    const int hh = gcol >> 6, hd = gcol & 63;
                    long o = (long)z * strideOut;
                    if (z == 2) o += (((long)b * kH + hh) * kHD + hd) * kT + t;  // VT
                    else        o += (((long)b * kH + hh) * kT + t) * kHD + hd;  // Q/K
                    outb[o] = (bf16)v;
                } else {
                    v += bi[gcol];
                    resid[(long)grow * N + gcol] += v;
                }
            }
}

// ---------------------------------------------------------------------------
// Fused FF: ln2 + FF1(relu) + FF2(+=X) + NEXT LayerNorm (ln1[l+1] or lnf),
// one block per 16 rows, 4 waves. Block owns complete rows, so after the
// X += (phase C) and a __syncthreads (drains vmcnt -> block-local global
// visibility), phase D re-reads the L1/L2-hot rows and writes Hout.
// ---------------------------------------------------------------------------
__global__ __launch_bounds__(256, 2)
void ff_fused(float* __restrict__ X, const float* __restrict__ g,
              const float* __restrict__ be,
              const bf16* __restrict__ W1T_, const float* __restrict__ b1_,
              const bf16* __restrict__ W2T_, const float* __restrict__ b2_,
              const float* __restrict__ gn, const float* __restrict__ bn,
              bf16* __restrict__ Hout)
{
    __shared__ __align__(16) bf16 Hs[16 * kC];
    __shared__ __align__(16) bf16 F1s[16 * kFFP];
    const int tid = threadIdx.x, lane = tid & 63, w = tid >> 6;
    const int lr = lane & 15, lg = lane >> 4;
    const int r0 = blockIdx.x * 16;

    // Phase A: ln2 on rows r0..r0+15 -> Hs (16B-block XOR swizzle by row&7)
    {
        const int row = tid >> 4, c16 = tid & 15;
        float4 xv[16];
        float s1 = 0.f, s2 = 0.f;
#pragma unroll
        for (int p = 0; p < 8; ++p) {
            const float* base = &X[(long)(r0 + row) * kC + p * 128 + c16 * 8];
            xv[2 * p]     = *(const float4*)base;
            xv[2 * p + 1] = *(const float4*)(base + 4);
#pragma unroll
            for (int e = 0; e < 4; ++e) {
                float a0 = ((const float*)&xv[2 * p])[e], a1 = ((const float*)&xv[2 * p + 1])[e];
                s1 += a0 + a1; s2 += a0 * a0 + a1 * a1;
            }
        }
#pragma unroll
        for (int off = 1; off < 16; off <<= 1) { s1 += __shfl_xor(s1, off); s2 += __shfl_xor(s2, off); }
        const float mean = s1 * (1.f / kC);
        const float rstd = rsqrtf(s2 * (1.f / kC) - mean * mean + 1e-5f);
#pragma unroll
        for (int p = 0; p < 8; ++p) {
            const int c0 = p * 128 + c16 * 8;
            float4 g0 = *(const float4*)&g[c0],  g1 = *(const float4*)&g[c0 + 4];
            float4 b0 = *(const float4*)&be[c0], b1v = *(const float4*)&be[c0 + 4];
            float h[8];
#pragma unroll
            for (int e = 0; e < 4; ++e) {
                h[e]     = (((const float*)&xv[2 * p])[e]     - mean) * rstd * ((const float*)&g0)[e] + ((const float*)&b0)[e];
                h[4 + e] = (((const float*)&xv[2 * p + 1])[e] - mean) * rstd * ((const float*)&g1)[e] + ((const float*)&b1v)[e];
            }
            uint4 hv;
            hv.x = bpack(h[0], h[1]); hv.y = bpack(h[2], h[3]);
            hv.z = bpack(h[4], h[5]); hv.w = bpack(h[6], h[7]);
            const int cb = c16 + p * 16;
            *(uint4*)&Hs[row * kC + ((cb ^ (row & 7)) << 3)] = hv;
        }
    }
    __syncthreads();

    // Phase B: FF1 f1[16][128] = relu(Hs @ W1T + b1) -> F1s (swizzled)
    {
        f32x4 accA[2], accB[2];
#pragma unroll
        for (int j = 0; j < 2; ++j) { accA[j] = (f32x4){0,0,0,0}; accB[j] = (f32x4){0,0,0,0}; }
        for (int k0 = 0; k0 < kC; k0 += 64) {
            const bf16x8 a0 = *(const bf16x8*)&Hs[lr * kC + ((((k0 >> 3) + 0 * 4 + lg) ^ (lr & 7)) << 3)];
            const bf16x8 a1 = *(const bf16x8*)&Hs[lr * kC + ((((k0 >> 3) + 1 * 4 + lg) ^ (lr & 7)) << 3)];
#pragma unroll
            for (int j = 0; j < 2; ++j) {
                const bf16x8 b0 = *(const bf16x8*)&W1T_[(long)(w * 32 + j * 16 + lr) * kC + k0 + 0 * 32 + lg * 8];
                const bf16x8 b1 = *(const bf16x8*)&W1T_[(long)(w * 32 + j * 16 + lr) * kC + k0 + 1 * 32 + lg * 8];
                accA[j] = __builtin_amdgcn_mfma_f32_16x16x32_bf16(a0, b0, accA[j], 0, 0, 0);
                accB[j] = __builtin_amdgcn_mfma_f32_16x16x32_bf16(a1, b1, accB[j], 0, 0, 0);
            }
        }
#pragma unroll
        for (int j = 0; j < 2; ++j)
#pragma unroll
            for (int rr = 0; rr < 4; ++rr) {
                const int row = lg * 4 + rr, col = w * 32 + j * 16 + lr;
                float v = accA[j][rr] + accB[j][rr] + (col < kFF ? b1_[col] : 0.f);
                F1s[row * kFFP + (((col >> 3) ^ (row & 7)) << 3) + (col & 7)] = (bf16)fmaxf(v, 0.f);
            }
    }
    __syncthreads();

    // Phase C: FF2  X[16][1024] += F1s @ W2T + b2   (8 n-chunks of 128)
    for (int nc = 0; nc < 8; ++nc) {
        f32x4 acc[2];
        acc[0] = (f32x4){0.f, 0.f, 0.f, 0.f};
        acc[1] = (f32x4){0.f, 0.f, 0.f, 0.f};
#pragma unroll
        for (int kk = 0; kk < 4; ++kk) {
            const bf16x8 a = *(const bf16x8*)&F1s[lr * kFFP + (((kk * 4 + lg) ^ (lr & 7)) << 3)];
#pragma unroll
            for (int j = 0; j < 2; ++j) {
                const bf16x8 bv = *(const bf16x8*)&W2T_[(long)(nc * 128 + w * 32 + j * 16 + lr) * kFFP + kk * 32 + lg * 8];
                acc[j] = __builtin_amdgcn_mfma_f32_16x16x32_bf16(a, bv, acc[j], 0, 0, 0);
            }
        }
#pragma unroll
        for (int j = 0; j < 2; ++j)
#pragma unroll
            for (int rr = 0; rr < 4; ++rr) {
                const int row = r0 + lg * 4 + rr, col = nc * 128 + w * 32 + j * 16 + lr;
                X[(long)row * kC + col] += acc[j][rr] + b2_[col];
            }
    }
    __syncthreads();   // drains vmcnt: block's X writes visible to block

    // Phase D: NEXT LayerNorm (ln1[l+1] / lnf) on the updated rows -> Hout
    {
        const int row = tid >> 4, c16 = tid & 15;
        float4 xv[16];
        float s1 = 0.f, s2 = 0.f;
#pragma unroll
        for (int p = 0; p < 8; ++p) {
            const float* base = &X[(long)(r0 + row) * kC + p * 128 + c16 * 8];
            xv[2 * p]     = *(const float4*)base;
            xv[2 * p + 1] = *(const float4*)(base + 4);
#pragma unroll
            for (int e = 0; e < 4; ++e) {
                float a0 = ((const float*)&xv[2 * p])[e], a1 = ((const float*)&xv[2 * p + 1])[e];
                s1 += a0 + a1; s2 += a0 * a0 + a1 * a1;
            }
        }
#pragma unroll
        for (int off = 1; off < 16; off <<= 1) { s1 += __shfl_xor(s1, off); s2 += __shfl_xor(s2, off); }
        const float mean = s1 * (1.f / kC);
        const float rstd = rsqrtf(s2 * (1.f / kC) - mean * mean + 1e-5f);
#pragma unroll
        for (int p = 0; p < 8; ++p) {
            const int c0 = p * 128 + c16 * 8;
            float4 g0 = *(const float4*)&gn[c0], g1 = *(const float4*)&gn[c0 + 4];
            float4 b0 = *(const float4*)&bn[c0], b1v = *(const float4*)&bn[c0 + 4];
            float h[8];
#pragma unroll
            for (int e = 0; e < 4; ++e) {
                h[e]     = (((const float*)&xv[2 * p])[e]     - mean) * rstd * ((const float*)&g0)[e] + ((const float*)&b0)[e];
                h[4 + e] = (((const float*)&xv[2 * p + 1])[e] - mean) * rstd * ((const float*)&g1)[e] + ((const float*)&b1v)[e];
            }
            uint4 hv;
            hv.x = bpack(h[0], h[1]); hv.y = bpack(h[2], h[3]);
            hv.z = bpack(h[4], h[5]); hv.w = bpack(h[6], h[7]);
            *(uint4*)&Hout[(long)(r0 + row) * kC + c0] = hv;
        }
    }
}

// ---------------------------------------------------------------------------
// Fused attention v14 (R16 best): depth-2 REGISTER prefetch.
// ---------------------------------------------------------------------------
__global__ __launch_bounds__(256, 2)
void attn_fused(const bf16* __restrict__ Qg, const bf16* __restrict__ Kg,
                const bf16* __restrict__ VTg, bf16* __restrict__ yg,
                float* __restrict__ attm)
{
    __shared__ __align__(16) bf16 SH[32768];   // 64 KB total
    bf16* Klds = SH;                           // 2 bufs x [64][64]
    bf16* Vlds = SH + 8192;                    // 2 bufs x [64][64]
    bf16* Ps   = SH + 16384;                   // [16][1024] swizzled E
    __shared__ __align__(16) float reds[16][4];
    __shared__ float invs[16];
    const int tid = threadIdx.x, lane = tid & 63, w = tid >> 6;   // w 0..3
    const int lr = lane & 15, lg = lane >> 4;
    const int bid = blockIdx.x, r_ = bid >> 3;
    const int h = ((bid & 7) << 1) | (r_ & 1);    // XCD-local head
    const int q0 = (r_ >> 1) * 16;

    const int sr  = lane >> 3;                 // staging row within 8-row chunk
    const int gcb = (lane & 7) ^ sr;           // inverse-swizzled src col-block
    const int loB = (lg & 1) * 4;
    const int rowb = w * 16 + sr;
    const int ldK0 = (w * 16) * 64, ldK1 = (w * 16 + 8) * 64;
    const int wr8 = lane * 8;                  // thread's 16B slot within chunk

    unsigned am_[16][2];                       // attm acc (q=lr), packed bf16x2
#pragma unroll
    for (int j = 0; j < 16; ++j) { am_[j][0] = 0u; am_[j][1] = 0u; }

    for (int b = 0; b < kB; ++b) {
        const long bh = (long)b * kH + h;
        const bf16* Qb = Qg + (bh * kT + q0) * kHD;
        const bf16* Kb = Kg + bh * kT * kHD;
        const bf16* Vb = VTg + bh * (long)kHD * kT;

        // Q fragments (tiny, L2-hot)
        const bf16x8 qf0 = *(const bf16x8*)&Qb[lr * kHD + lg * 8];
        const bf16x8 qf1 = *(const bf16x8*)&Qb[lr * kHD + 32 + lg * 8];

        // ---- warmup: reg-load tiles 0 (set A) and 1 (set B); write tile 0
        uint4 kA0 = *(const uint4*)(Kb + (rowb)     * kHD + gcb * 8);
        uint4 kA1 = *(const uint4*)(Kb + (rowb + 8) * kHD + gcb * 8);
        uint4 vA0 = *(const uint4*)(Vb + (long)(rowb)     * kT + gcb * 8);
        uint4 vA1 = *(const uint4*)(Vb + (long)(rowb + 8) * kT + gcb * 8);
        uint4 kB0 = *(const uint4*)(Kb + (64 + rowb)     * kHD + gcb * 8);
        uint4 kB1 = *(const uint4*)(Kb + (64 + rowb + 8) * kHD + gcb * 8);
        uint4 vB0 = *(const uint4*)(Vb + (long)(rowb)     * kT + 64 + gcb * 8);
        uint4 vB1 = *(const uint4*)(Vb + (long)(rowb + 8) * kT + 64 + gcb * 8);
        *(uint4*)&Klds[ldK0 + wr8] = kA0;
        *(uint4*)&Klds[ldK1 + wr8] = kA1;
        *(uint4*)&Vlds[ldK0 + wr8] = vA0;
        *(uint4*)&Vlds[ldK1 + wr8] = vA1;

        float s = 0.f;
        f32x4 y0 = (f32x4){0.f, 0.f, 0.f, 0.f};
        f32x4 y1 = (f32x4){0.f, 0.f, 0.f, 0.f};

#pragma unroll
        for (int kt = 0; kt < 16; ++kt) {
            const int cur = (kt & 1) * 4096;
            const int nxt = 4096 - cur;
            // 1) issue reg loads for tile kt+2 into the set freed last iter
            if (kt < 14) {
                const int kn = (kt + 2) * 64;
                if ((kt & 1) == 0) {
                    kA0 = *(const uint4*)(Kb + (kn + rowb)     * kHD + gcb * 8);
                    kA1 = *(const uint4*)(Kb + (kn + rowb + 8) * kHD + gcb * 8);
                    vA0 = *(const uint4*)(Vb + (long)(rowb)     * kT + kn + gcb * 8);
                    vA1 = *(const uint4*)(Vb + (long)(rowb + 8) * kT + kn + gcb * 8);
                } else {
                    kB0 = *(const uint4*)(Kb + (kn + rowb)     * kHD + gcb * 8);
                    kB1 = *(const uint4*)(Kb + (kn + rowb + 8) * kHD + gcb * 8);
                    vB0 = *(const uint4*)(Vb + (long)(rowb)     * kT + kn + gcb * 8);
                    vB1 = *(const uint4*)(Vb + (long)(rowb + 8) * kT + kn + gcb * 8);
                }
            }

            // 2) QK^T from buf[cur] (own-wave K rows)
            const int krow = w * 16 + lr;
            const bf16x8 kf0 = *(const bf16x8*)&Klds[cur + krow * 64 + (((0 + lg) ^ (lr & 7)) << 3)];
            const bf16x8 kf1 = *(const bf16x8*)&Klds[cur + krow * 64 + (((4 + lg) ^ (lr & 7)) << 3)];
            f32x4 a = (f32x4){0.f, 0.f, 0.f, 0.f};
            a = __builtin_amdgcn_mfma_f32_16x16x32_bf16(kf0, qf0, a, 0, 0, 0);
            a = __builtin_amdgcn_mfma_f32_16x16x32_bf16(kf1, qf1, a, 0, 0, 0);
            const float e0 = exp2f(a[0]), e1 = exp2f(a[1]);
            const float e2 = exp2f(a[2]), e3 = exp2f(a[3]);
            s += (e0 + e1) + (e2 + e3);
            const int tb = kt * 8 + w * 2 + (lg >> 1);
            uint2 pk; pk.x = bpack(e0, e1); pk.y = bpack(e2, e3);
            *(uint2*)&Ps[lr * kT + ((tb ^ (lr & 7)) << 3) + loB] = pk;

            // 3) write tile kt+1 regs -> buf[nxt] (compiler inserts counted vmcnt)
            if (kt < 15) {
                if ((kt & 1) == 0) {
                    *(uint4*)&Klds[nxt + ldK0 + wr8] = kB0;
                    *(uint4*)&Klds[nxt + ldK1 + wr8] = kB1;
                    *(uint4*)&Vlds[nxt + ldK0 + wr8] = vB0;
                    *(uint4*)&Vlds[nxt + ldK1 + wr8] = vB1;
                } else {
                    *(uint4*)&Klds[nxt + ldK0 + wr8] = kA0;
                    *(uint4*)&Klds[nxt + ldK1 + wr8] = kA1;
                    *(uint4*)&Vlds[nxt + ldK0 + wr8] = vA0;
                    *(uint4*)&Vlds[nxt + ldK1 + wr8] = vA1;
                }
            }

            // 4) single barrier: E cross-wave visible (lgkm only)
            asm volatile("s_waitcnt lgkmcnt(0)" ::: "memory");
            __builtin_amdgcn_s_barrier();
            __builtin_amdgcn_sched_barrier(0);

            // 5) PV from buf[cur] (own-wave V rows) + Ps; dual chains
            const int vrow = w * 16 + lr;
            const bf16x8 a0 = *(const bf16x8*)&Ps[lr * kT + (((kt * 8 + 0 + lg) ^ (lr & 7)) << 3)];
            const bf16x8 v0 = *(const bf16x8*)&Vlds[cur + vrow * 64 + (((0 + lg) ^ (lr & 7)) << 3)];
            const bf16x8 a1 = *(const bf16x8*)&Ps[lr * kT + (((kt * 8 + 4 + lg) ^ (lr & 7)) << 3)];
            const bf16x8 v1 = *(const bf16x8*)&Vlds[cur + vrow * 64 + (((4 + lg) ^ (lr & 7)) << 3)];
            y0 = __builtin_amdgcn_mfma_f32_16x16x32_bf16(a0, v0, y0, 0, 0, 0);
            y1 = __builtin_amdgcn_mfma_f32_16x16x32_bf16(a1, v1, y1, 0, 0, 0);
        }

        // row sums -> inv
        s += __shfl_xor(s, 16);
        s += __shfl_xor(s, 32);
        if (lane < 16) reds[lane][w] = s;
        asm volatile("s_waitcnt lgkmcnt(0)" ::: "memory");
        __builtin_amdgcn_s_barrier();
        __builtin_amdgcn_sched_barrier(0);
        float4 rv = *(const float4*)&reds[lr][0];
        const float inv = __builtin_amdgcn_rcpf((rv.x + rv.y) + (rv.z + rv.w));
        const float iv4 = inv * 0.25f;
        if (lane < 16) invs[lane] = inv;

        // am += E * inv/4  (read back own-thread E dwords)
#pragma unroll
        for (int kt = 0; kt < 16; ++kt) {
            const int tb = kt * 8 + w * 2 + (lg >> 1);
            uint2 e2v = *(const uint2*)&Ps[lr * kT + ((tb ^ (lr & 7)) << 3) + loB];
#pragma unroll
            for (int d = 0; d < 2; ++d) {
                unsigned ev = d ? e2v.y : e2v.x;
                unsigned av = am_[kt][d];
                float n0 = blo(av) + blo(ev) * iv4;
                float n1 = bhi(av) + bhi(ev) * iv4;
                am_[kt][d] = bpack(n0, n1);
            }
        }

        // y write (row q = lg*4+rr, col d = w*16+lr)
#pragma unroll
        for (int rr = 0; rr < 4; ++rr) {
            const float iv = invs[lg * 4 + rr];
            yg[((long)b * kT + q0 + lg * 4 + rr) * kC + h * kHD + w * 16 + lr]
                = (bf16)((y0[rr] + y1[rr]) * iv);
        }
    }

    __syncthreads();   // all Ps/K/V reads done before fp32 reuse of SH
    // attm epilogue: stage [16][1024] fp32 in SH, stream out coalesced
    float* amf = (float*)SH;
#pragma unroll
    for (int kt = 0; kt < 16; ++kt)
#pragma unroll
        for (int d = 0; d < 2; ++d) {
            unsigned av = am_[kt][d];
            const int col = kt * 64 + w * 16 + lg * 4 + 2 * d;
            amf[lr * kT + col]     = blo(av);
            amf[lr * kT + col + 1] = bhi(av);
        }
    __syncthreads();
#pragma unroll
    for (int p = 0; p < 16; ++p) {
        const int f = p * 256 + tid;              // 4096 float4s
        const int row = f >> 8, c4 = f & 255;
        float4 v = *(const float4*)&amf[row * kT + c4 * 4];
        *(float4*)&attm[((long)h * kT + q0 + row) * kT + c4 * 4] = v;
    }
}

// pooled[b][c] = mean_t hb[b,t,c]  (bf16 input)
__global__ __launch_bounds__(256)
void pool_kernel(const bf16* __restrict__ hb, float* __restrict__ pooled)
{
    const int c = blockIdx.x * 256 + threadIdx.x;
    const int b = blockIdx.y;
    const int t0 = blockIdx.z * 128;
    float s = 0.f;
    for (int t = t0; t < t0 + 128; ++t) s += (float)hb[((long)b * kT + t) * kC + c];
    atomicAdd(&pooled[b * kC + c], s * (1.f / kT));
}

// ---------------------------------------------------------------------------
extern "C" void kernel_launch(void* const* d_in, const int* in_sizes, int n_in,
                              void* d_out, int out_size, void* d_ws, size_t ws_size,
                              hipStream_t stream)
{
    const int*   idx  = (const int*)d_in[0];
    const float* tok  = (const float*)d_in[1];
    const float* pos  = (const float*)d_in[2];
    const float* Wq   = (const float*)d_in[3];
    const float* bq   = (const float*)d_in[4];
    const float* Wk   = (const float*)d_in[5];
    const float* bk   = (const float*)d_in[6];
    const float* Wv   = (const float*)d_in[7];
    const float* bv   = (const float*)d_in[8];
    const float* Wo   = (const float*)d_in[9];
    const float* bo   = (const float*)d_in[10];
    const float* ln1w = (const float*)d_in[11];
    const float* ln1b = (const float*)d_in[12];
    const float* ln2w = (const float*)d_in[13];
    const float* ln2b = (const float*)d_in[14];
    const float* W1   = (const float*)d_in[15];
    const float* b1   = (const float*)d_in[16];
    const float* W2   = (const float*)d_in[17];
    const float* b2   = (const float*)d_in[18];
    const float* lnfw = (const float*)d_in[19];
    const float* lnfb = (const float*)d_in[20];

    char* ws = (char*)d_ws;
    long off = 0;
    auto alloc = [&](long bytes) { char* p = ws + off; off += (bytes + 255) & ~255L; return p; };
    bf16*  WQKVT = (bf16*)alloc((long)kL * 3 * kC * kC * 2);
    bf16*  WOT   = (bf16*)alloc((long)kL * kC * kC * 2);
    bf16*  W1T   = (bf16*)alloc((long)kL * kFFP * kC * 2);
    bf16*  W2T   = (bf16*)alloc((long)kL * kC * kFFP * 2);
    float* BQKV  = (float*)alloc((long)kL * 3 * kC * 4);
    float* X     = (float*)alloc((long)kM * kC * 4);
    bf16*  Hbuf  = (bf16*)alloc((long)kM * kC * 2);
    bf16*  QKV   = (bf16*)alloc(3L * kM * kC * 2);
    bf16*  Y     = (bf16*)alloc((long)kM * kC * 2);

    float* pooled = (float*)d_out;
    float* attm_base = pooled + kB * kC;

    prep_kernel<<<17472, 256, 0, stream>>>(Wq, Wk, Wv, Wo, W1, W2, bq, bk, bv,
                                           WQKVT, WOT, W1T, W2T, BQKV, pooled);
    // embed + ln1[0] -> Hbuf
    embed_kernel<<<kM, 256, 0, stream>>>(idx, tok, pos, X, ln1w, ln1b, Hbuf);

    for (int l = 0; l < kL; ++l) {
        gemm_bf16<2, 2, 4, 4, 0, 1><<<dim3(8, 32, 3), 256, 0, stream>>>(
            Hbuf, 0L, WQKVT + (long)l * 3 * kC * kC, (long)kC * kC,
            BQKV + l * 3 * kC, kC, QKV, (long)kM * kC, nullptr,
            kC, kC, kC, kC);
        attn_fused<<<dim3(1024), 256, 0, stream>>>(
            QKV, QKV + (long)kM * kC, QKV + 2L * kM * kC, Y,
            attm_base + (long)l * kH * kT * kT);
        gemm_bf16<2, 2, 4, 4, 4, 1><<<dim3(8, 32, 1), 256, 0, stream>>>(
            Y, 0L, WOT + (long)l * kC * kC, 0L, bo + l * kC, 0,
            nullptr, 0L, X, kC, kC, kC, kC);
        // ff + NEXT layer-norm: ln1[l+1] for l<3, lnf for l==3 -> Hbuf
        const float* gn = (l < kL - 1) ? (ln1w + (l + 1) * kC) : lnfw;
        const float* bn = (l < kL - 1) ? (ln1b + (l + 1) * kC) : lnfb;
        ff_fused<<<256, 256, 0, stream>>>(X, ln2w + l * kC, ln2b + l * kC,
                                          W1T + (long)l * kFFP * kC, b1 + l * kFF,
                                          W2T + (long)l * kC * kFFP, b2 + l * kC,
                                          gn, bn, Hbuf);
    }
    pool_kernel<<<dim3(4, kB, 8), 256, 0, stream>>>(Hbuf, pooled);
}